// Round 12
// baseline (403.719 us; speedup 1.0000x reference)
//
#include <hip/hip_runtime.h>
#include <stdint.h>

#define HD 768
#define NHEADS 12
#define DHEAD 64
#define BATCH 8
#define TLEN 64
#define ILEN 197
#define NPAIRS 100864   // = 394*256 exactly
#define MTILES 394

typedef __attribute__((ext_vector_type(8))) short short8;
typedef __attribute__((ext_vector_type(4))) float f32x4;

__device__ __forceinline__ short f2bf(float x) {
    union { float f; uint32_t u; } v; v.f = x;
    uint32_t r = v.u + 0x7FFFu + ((v.u >> 16) & 1u);
    return (short)(r >> 16);
}
__device__ __forceinline__ float bf2f(short s) {
    union { uint32_t u; float f; } v; v.u = ((uint32_t)(unsigned short)s) << 16;
    return v.f;
}
__device__ __forceinline__ uint32_t cvtpk(float lo, float hi) {
    uint32_t r;
    asm("v_cvt_pk_bf16_f32 %0, %1, %2" : "=v"(r) : "v"(lo), "v"(hi));
    return r;
}
__device__ __forceinline__ void gll16(const void* g, void* l) {
    __builtin_amdgcn_global_load_lds(
        (const __attribute__((address_space(1))) unsigned int*)g,
        (__attribute__((address_space(3))) unsigned int*)l, 16, 0, 0);
}

// ---------------------------------------------------------------------------
// Prep: W5s proj chunks (unchanged) + W1Bs gate-GEMM B chunks (R7 format).
// ---------------------------------------------------------------------------
__global__ __launch_bounds__(256) void prep_weights(
    const float* __restrict__ Wq, const float* __restrict__ Wk,
    const float* __restrict__ Wv, const float* __restrict__ Wt,
    const float* __restrict__ Wi, const float* __restrict__ W1,
    short* __restrict__ W5s, short* __restrict__ W1Bs)
{
    __shared__ float tile[64][65];
    int bx = blockIdx.x;
    int tid = threadIdx.x;
    if (bx >= 720) {
        int idx = bx - 720;            // 0..35
        int pn = idx / 12, kt = idx - pn * 12;
        int c = tid;                   // col 0..255
        int j = pn * 256 + c;
        char* dst = (char*)W1Bs + (size_t)idx * 32768 + c * 128;
        int swz = (c & 7) << 4;
#pragma unroll
        for (int kg = 0; kg < 8; ++kg) {
            short8 o;
#pragma unroll
            for (int e = 0; e < 8; ++e)
                o[e] = f2bf(W1[(size_t)(kt * 64 + kg * 8 + e) * HD + j]);
            *(short8*)(dst + ((kg * 16) ^ swz)) = o;
        }
        return;
    }
    int seg = bx / 144, ti = bx - seg * 144;
    const float* src = (seg == 0) ? Wt : (seg == 1) ? Wq : (seg == 2) ? Wi
                     : (seg == 3) ? Wk : Wv;
    int kt = ti / 12, ntile = ti - kt * 12;
#pragma unroll
    for (int pass = 0; pass < 16; ++pass) {
        int idx = pass * 256 + tid;
        int kk = idx >> 6, nn = idx & 63;
        tile[kk][nn] = src[(size_t)(kt * 64 + kk) * HD + ntile * 64 + nn];
    }
    __syncthreads();
    size_t base = ((size_t)(seg * 12 + ntile) * 12 + kt) * 8192;
#pragma unroll
    for (int pass = 0; pass < 16; ++pass) {
        int idx = pass * 256 + tid;
        int col = idx >> 6, kloc = idx & 63;
        float x = tile[kloc][col];
        short h = f2bf(x);
        short lw = f2bf(x - bf2f(h));
        int sidx = (col * 64 + kloc) ^ ((col & 7) << 3);
        W5s[base + sidx] = h;
        W5s[base + 4096 + sidx] = lw;
    }
}

// ---------------------------------------------------------------------------
// Projection GEMM (hi/lo bf16 split, near-fp32) — unchanged from R3.
// ---------------------------------------------------------------------------
__global__ __launch_bounds__(256, 1) void proj_kernel(
    const float* __restrict__ X, int M,
    const short* __restrict__ W5s, int segbase,
    const float* __restrict__ bias0, const float* __restrict__ bias1,
    const float* __restrict__ bias2,
    float* __restrict__ out0, float* __restrict__ out1, float* __restrict__ out2)
{
    __shared__ __align__(16) short Bs[2][8192];
    int tid = threadIdx.x;
    int l = tid & 63, w = tid >> 6;
    int lo = l & 15, grp = l >> 4;
    int y = blockIdx.y;
    int segl = y / 12, ntile = y - segl * 12;
    int seg = segbase + segl;
    const char* wsrc = (const char*)W5s + (size_t)((seg * 12 + ntile) * 12) * 16384;
    {
        const char* s = wsrc + w * 4096 + l * 16;
        char* d = (char*)&Bs[0][0] + w * 4096;
        gll16(s, d); gll16(s + 1024, d + 1024);
        gll16(s + 2048, d + 2048); gll16(s + 3072, d + 3072);
    }
    int arow = blockIdx.x * 64 + w * 16 + lo;
    bool aok = arow < M;
    const float* xrow = X + (size_t)(aok ? arow : 0) * HD;
    short8 ah[24], al[24];
#pragma unroll
    for (int kc = 0; kc < 24; ++kc) {
        int kb = kc * 32 + grp * 8;
        float4 xa = {0.f, 0.f, 0.f, 0.f}, xb = {0.f, 0.f, 0.f, 0.f};
        if (aok) { xa = *(const float4*)(xrow + kb); xb = *(const float4*)(xrow + kb + 4); }
        float xs[8] = {xa.x, xa.y, xa.z, xa.w, xb.x, xb.y, xb.z, xb.w};
#pragma unroll
        for (int e = 0; e < 8; ++e) {
            short hh = f2bf(xs[e]);
            ah[kc][e] = hh;
            al[kc][e] = f2bf(xs[e] - bf2f(hh));
        }
    }
    __syncthreads();

    f32x4 acc[4];
    f32x4 z4 = {0.f, 0.f, 0.f, 0.f};
#pragma unroll
    for (int js = 0; js < 4; ++js) acc[js] = z4;

#pragma unroll
    for (int kk = 0; kk < 12; ++kk) {
        const short* buf = &Bs[kk & 1][0];
        if (kk < 11) {
            const char* s = wsrc + (size_t)(kk + 1) * 16384 + w * 4096 + l * 16;
            char* d = (char*)&Bs[(kk + 1) & 1][0] + w * 4096;
            gll16(s, d); gll16(s + 1024, d + 1024);
            gll16(s + 2048, d + 2048); gll16(s + 3072, d + 3072);
            asm volatile("s_waitcnt vmcnt(4)" ::: "memory");
        } else {
            asm volatile("s_waitcnt vmcnt(0)" ::: "memory");
        }
        __builtin_amdgcn_s_barrier();
        asm volatile("" ::: "memory");
#pragma unroll
        for (int js = 0; js < 4; ++js) {
            int col = js * 16 + lo;
            int base = col * 64;
            int sw = (col & 7) << 3;
#pragma unroll
            for (int kcl = 0; kcl < 2; ++kcl) {
                int idx = (base + kcl * 32 + grp * 8) ^ sw;
                short8 bh = *(const short8*)&buf[idx];
                short8 bl = *(const short8*)&buf[4096 + idx];
                int kc = kk * 2 + kcl;
                acc[js] = __builtin_amdgcn_mfma_f32_16x16x32_bf16(ah[kc], bh, acc[js], 0, 0, 0);
                acc[js] = __builtin_amdgcn_mfma_f32_16x16x32_bf16(ah[kc], bl, acc[js], 0, 0, 0);
                acc[js] = __builtin_amdgcn_mfma_f32_16x16x32_bf16(al[kc], bh, acc[js], 0, 0, 0);
            }
        }
        asm volatile("s_waitcnt lgkmcnt(0)" ::: "memory");
        __builtin_amdgcn_s_barrier();
        asm volatile("" ::: "memory");
    }
    const float* bp = (segl == 0) ? bias0 : (segl == 1) ? bias1 : bias2;
    float* op = (segl == 0) ? out0 : (segl == 1) ? out1 : out2;
#pragma unroll
    for (int js = 0; js < 4; ++js) {
        int cc = ntile * 64 + js * 16 + lo;
        float bvv = bp[cc];
#pragma unroll
        for (int r = 0; r < 4; ++r) {
            int orow = blockIdx.x * 64 + w * 16 + grp * 4 + r;
            if (orow < M) op[(size_t)orow * HD + cc] = acc[js][r] + bvv;
        }
    }
}

// ---------------------------------------------------------------------------
// gate_gemm: 256x256 tile, BK=64, 8 waves (2Mx4N), per-wave 128x64 out.
// R12 = R11 fusion, repaired: constructA(kt+1) issues at the TOP of the
// K-tile body (global loads get the whole MFMA phase as cover; WAR safe —
// npar's reads finished at the kt-1 boundary), and f32->bf16 uses the HW
// v_cvt_pk_bf16_f32 (RNE, bitwise == f2bf) cutting construct VALU ~5x.
// ---------------------------------------------------------------------------
__global__ __launch_bounds__(512, 2) void gate_gemm(
    const float* __restrict__ te, const float* __restrict__ ie,
    const short* __restrict__ W1Bs, const float* __restrict__ b1,
    const float* __restrict__ W2, float* __restrict__ plg)
{
    __shared__ __align__(16) char lds[131072];   // A dbuf [0,64K), B dbuf [64K,128K)
    int tid = threadIdx.x;
    int lane = tid & 63, wid = tid >> 6;
    int lo = lane & 15, grp = lane >> 4;
    int wr = wid >> 2, wc = wid & 3;
    // bijective XCD swizzle (m204): hw bx -> logical id
    int bx0 = blockIdx.x;
    int nwg = gridDim.x;
    int qq = nwg >> 3, rr8 = nwg & 7;
    int xcd = bx0 & 7;
    int logical = (xcd < rr8 ? xcd * (qq + 1) : rr8 * (qq + 1) + (xcd - rr8) * qq)
                + (bx0 >> 3);
    int m_l = logical / 3, pn = logical - m_l * 3;

    const char* Bg = (const char*)W1Bs + (size_t)pn * 12 * 32768;

    // ---- per-lane construct-row decode (once) ----
    int crow = wid * 32 + (lane >> 1);     // A row 0..255 this lane builds
    int ckh  = lane & 1;                   // k-half (32 k) within BK=64
    int cp = m_l * 256 + crow;             // global pair id (< NPAIRS always)
    int cb = cp / 12608; int crr = cp - cb * 12608;
    int ct_ = crr / 197; int ci = crr - ct_ * 197;
    const float* ctp = te + (size_t)(cb * 64 + ct_) * HD + ckh * 32;
    const float* cip = ie + (size_t)(cb * 197 + ci) * HD + ckh * 32;
    int cawz = (crow & 7) << 4;
    int ckg0 = ckh * 4;

    // construct A(t) into A-buffer `par` (HW cvt_pk, 2 elems/instr)
    auto constructA = [&](int t, int par) {
        const float* tpk = ctp + (size_t)t * 64;
        const float* ipk = cip + (size_t)t * 64;
        char* ab = lds + par * 32768 + crow * 128;
#pragma unroll
        for (int g = 0; g < 4; ++g) {
            float4 ta = *(const float4*)(tpk + g * 8);
            float4 tb = *(const float4*)(tpk + g * 8 + 4);
            float4 xa = *(const float4*)(ipk + g * 8);
            float4 xb = *(const float4*)(ipk + g * 8 + 4);
            uint32_t w0 = cvtpk(xa.x * ta.x, xa.y * ta.y);
            uint32_t w1 = cvtpk(xa.z * ta.z, xa.w * ta.w);
            uint32_t w2 = cvtpk(xb.x * tb.x, xb.y * tb.y);
            uint32_t w3 = cvtpk(xb.z * tb.z, xb.w * tb.w);
            uint4 o = {w0, w1, w2, w3};
            *(uint4*)(ab + (((ckg0 + g) * 16) ^ cawz)) = o;
        }
    };

    // prologue: build A(0) into par 0, stage B(0) into par 0
    constructA(0, 0);
    {
        const char* s = Bg + tid * 16;
        char* d = lds + 65536 + tid * 16;
        gll16(s, d); gll16(s + 8192, d + 8192);
        gll16(s + 16384, d + 16384); gll16(s + 24576, d + 24576);
    }
    asm volatile("s_waitcnt vmcnt(0) lgkmcnt(0)" ::: "memory");
    __builtin_amdgcn_s_barrier();
    asm volatile("" ::: "memory");

    f32x4 acc[8][4];
    f32x4 z4 = {0.f, 0.f, 0.f, 0.f};
#pragma unroll
    for (int rt = 0; rt < 8; ++rt)
#pragma unroll
        for (int ct = 0; ct < 4; ++ct) acc[rt][ct] = z4;
    int swz = (lo & 7) << 4;

    for (int kt = 0; kt < 12; ++kt) {
        int par = kt & 1, npar = par ^ 1;
        int aoff = par * 32768;
        int boff = 65536 + par * 32768;
        bool more = kt < 11;

        // construct A(kt+1) FIRST: loads issue now, covered by this tile's MFMA
        if (more) constructA(kt + 1, npar);
        // stage B(kt+1)
        if (more) {
            const char* s = Bg + (size_t)(kt + 1) * 32768 + tid * 16;
            char* d = lds + 65536 + npar * 32768 + tid * 16;
            gll16(s, d); gll16(s + 8192, d + 8192);
            gll16(s + 16384, d + 16384); gll16(s + 24576, d + 24576);
        }

        // B frags for this K-tile (reused across 4 quadrant phases)
        short8 bfr[4][2];
#pragma unroll
        for (int ct = 0; ct < 4; ++ct) {
            int c = wc * 64 + ct * 16 + lo;
#pragma unroll
            for (int ks = 0; ks < 2; ++ks)
                bfr[ct][ks] = *(const short8*)(lds + boff + c * 128 + ((ks * 64 + grp * 16) ^ swz));
        }
        // 4 quadrant phases, free-run within the K-tile
#pragma unroll
        for (int q = 0; q < 4; ++q) {
            short8 af[2][2];
#pragma unroll
            for (int i2 = 0; i2 < 2; ++i2) {
                int r = wr * 128 + (2 * q + i2) * 16 + lo;
#pragma unroll
                for (int ks = 0; ks < 2; ++ks)
                    af[i2][ks] = *(const short8*)(lds + aoff + r * 128 + ((ks * 64 + grp * 16) ^ swz));
            }
            __builtin_amdgcn_s_setprio(1);
#pragma unroll
            for (int i2 = 0; i2 < 2; ++i2)
#pragma unroll
                for (int ct = 0; ct < 4; ++ct)
#pragma unroll
                    for (int ks = 0; ks < 2; ++ks)
                        acc[2 * q + i2][ct] = __builtin_amdgcn_mfma_f32_16x16x32_bf16(
                            af[i2][ks], bfr[ct][ks], acc[2 * q + i2][ct], 0, 0, 0);
            __builtin_amdgcn_s_setprio(0);
        }

        // boundary: B(kt+1) staged + A(kt+1) ds_writes visible
        asm volatile("s_waitcnt vmcnt(0) lgkmcnt(0)" ::: "memory");
        __builtin_amdgcn_s_barrier();
        asm volatile("" ::: "memory");
    }

    // epilogue: h = relu(acc + b1); per-wave partial logit over its 64 cols
    float b1v[4], w2v[4];
#pragma unroll
    for (int ct = 0; ct < 4; ++ct) {
        int j = pn * 256 + wc * 64 + ct * 16 + lo;
        b1v[ct] = b1[j]; w2v[ct] = W2[j];
    }
    float pl[8][4];
#pragma unroll
    for (int rt = 0; rt < 8; ++rt)
#pragma unroll
        for (int r = 0; r < 4; ++r) {
            float s = 0.f;
#pragma unroll
            for (int ct = 0; ct < 4; ++ct)
                s += fmaxf(acc[rt][ct][r] + b1v[ct], 0.f) * w2v[ct];
            pl[rt][r] = s;
        }
#pragma unroll
    for (int msk = 1; msk <= 8; msk <<= 1)
#pragma unroll
        for (int rt = 0; rt < 8; ++rt)
#pragma unroll
            for (int r = 0; r < 4; ++r)
                pl[rt][r] += __shfl_xor(pl[rt][r], msk);

    // reduce the 4 wc-wave partials through (now dead) LDS
    __syncthreads();
    float* red = (float*)lds;                       // [8 wid][128 row]
    if (lo == 0) {
#pragma unroll
        for (int rt = 0; rt < 8; ++rt)
#pragma unroll
            for (int r = 0; r < 4; ++r)
                red[wid * 128 + rt * 16 + grp * 4 + r] = pl[rt][r];
    }
    __syncthreads();
    if (tid < 256) {
        int wr_ = tid >> 7, rl = tid & 127;
        float s = red[(wr_ * 4 + 0) * 128 + rl] + red[(wr_ * 4 + 1) * 128 + rl]
                + red[(wr_ * 4 + 2) * 128 + rl] + red[(wr_ * 4 + 3) * 128 + rl];
        plg[(size_t)pn * NPAIRS + (size_t)m_l * 256 + tid] = s;
    }
}

// ---------------------------------------------------------------------------
__global__ __launch_bounds__(256) void gate_fin(
    const float* __restrict__ plg, const float* __restrict__ b2,
    float* __restrict__ gateb)
{
    int idx = blockIdx.x * 256 + threadIdx.x;
    if (idx < NPAIRS) {
        float s = plg[idx] + plg[NPAIRS + idx] + plg[2 * NPAIRS + idx] + b2[0];
        gateb[idx] = 1.f / (1.f + __expf(-s));
    }
}

// ---------------------------------------------------------------------------
// Cross-attention, fp32 VALU. Grid = (b,h,t-quarter) = 384 blocks.
// R9 structure: softmax rows into p_s[w][i][4], single PV pass (1x v reads).
// ---------------------------------------------------------------------------
__global__ __launch_bounds__(256) void attn_kernel(
    const float* __restrict__ q, const float* __restrict__ k,
    const float* __restrict__ v, const float* __restrict__ gate,
    float* __restrict__ out)
{
    __shared__ float k_s[ILEN * 65];
    __shared__ float p_s[4][ILEN][4];   // [wave][i][tt]
    int bx = blockIdx.x;
    int tq = bx & 3;
    int h = (bx >> 2) % NHEADS;
    int b = bx / (4 * NHEADS);
    int tid = threadIdx.x;
    for (int idx = tid; idx < ILEN * DHEAD; idx += 256) {
        int i = idx >> 6, d = idx & 63;
        k_s[i * 65 + d] = k[(size_t)(b * ILEN + i) * HD + h * DHEAD + d];
    }
    __syncthreads();

    int l = tid & 63, w = tid >> 6;
    int tbase = tq * 16 + w * 4;

    for (int tt = 0; tt < 4; ++tt) {
        int t = tbase + tt;
        float qv = q[(size_t)(b * 64 + t) * HD + h * DHEAD + l];
        float s0 = 0.f, s1 = 0.f, s2 = 0.f, s3 = 0.f;
        int i0 = l, i1 = 64 + l, i2 = 128 + l;
        int i3c = (192 + l < ILEN) ? 192 + l : 0;
        for (int d = 0; d < 64; ++d) {
            float qd = __shfl(qv, d);
            s0 += qd * k_s[i0 * 65 + d];
            s1 += qd * k_s[i1 * 65 + d];
            s2 += qd * k_s[i2 * 65 + d];
            s3 += qd * k_s[i3c * 65 + d];
        }
        float sc[4] = {s0, s1, s2, s3};
        float m = -3.0e38f;
#pragma unroll
        for (int rep = 0; rep < 4; ++rep) {
            int i = rep * 64 + l;
            sc[rep] = (i < ILEN) ? sc[rep] * 0.125f : -3.0e38f;
            m = fmaxf(m, sc[rep]);
        }
        for (int mask = 32; mask >= 1; mask >>= 1) m = fmaxf(m, __shfl_xor(m, mask));
        float sum = 0.f;
#pragma unroll
        for (int rep = 0; rep < 4; ++rep) {
            float e = __expf(sc[rep] - m);
            sc[rep] = e;
            sum += e;
        }
        for (int mask = 32; mask >= 1; mask >>= 1) sum += __shfl_xor(sum, mask);
        float inv = 1.f / sum;
        const float* grow = gate + (size_t)(b * 64 + t) * ILEN;
#pragma unroll
        for (int rep = 0; rep < 4; ++rep) {
            int i = rep * 64 + l;
            if (i < ILEN) p_s[w][i][tt] = sc[rep] * inv * grow[i];
        }
    }
    // same wave writes & reads p_s -> no barrier needed

    float ctx[4] = {0.f, 0.f, 0.f, 0.f};
    const float* vbase = v + (size_t)(b * ILEN) * HD + h * DHEAD + l;
#pragma unroll 4
    for (int i = 0; i < ILEN; ++i) {
        float vv = vbase[(size_t)i * HD];
        float4 p4 = *(const float4*)&p_s[w][i][0];
        ctx[0] += p4.x * vv;
        ctx[1] += p4.y * vv;
        ctx[2] += p4.z * vv;
        ctx[3] += p4.w * vv;
    }
#pragma unroll
    for (int tt = 0; tt < 4; ++tt)
        out[(size_t)(b * 64 + tbase + tt) * HD + h * DHEAD + l] = ctx[tt];
}

// ---------------------------------------------------------------------------
extern "C" void kernel_launch(void* const* d_in, const int* in_sizes, int n_in,
                              void* d_out, int out_size, void* d_ws, size_t ws_size,
                              hipStream_t stream)
{
    const float* text  = (const float*)d_in[0];
    const float* image = (const float*)d_in[1];
    const float* Wq = (const float*)d_in[2];
    const float* bq = (const float*)d_in[3];
    const float* Wk = (const float*)d_in[4];
    const float* bk = (const float*)d_in[5];
    const float* Wv = (const float*)d_in[6];
    const float* bv = (const float*)d_in[7];
    const float* Wt = (const float*)d_in[8];
    const float* bt = (const float*)d_in[9];
    const float* Wi = (const float*)d_in[10];
    const float* bi = (const float*)d_in[11];
    const float* W1 = (const float*)d_in[12];
    const float* b1 = (const float*)d_in[13];
    const float* W2 = (const float*)d_in[14];
    const float* b2 = (const float*)d_in[15];
    float* out = (float*)d_out;

    char* ws = (char*)d_ws;
    size_t off = 0;
    auto carve = [&](size_t bytes) -> void* {
        void* p = (void*)(ws + off);
        off += (bytes + 255) & ~(size_t)255;
        return p;
    };
    short* W5s  = (short*)carve((size_t)5 * 144 * 8192 * 2);   // 11.8 MB
    short* W1Bs = (short*)carve((size_t)36 * 32768);           // 1.18 MB
    float* te    = (float*)carve((size_t)512 * 768 * 4);
    float* qb    = (float*)carve((size_t)512 * 768 * 4);
    float* ieb   = (float*)carve((size_t)1576 * 768 * 4);
    float* kb    = (float*)carve((size_t)1576 * 768 * 4);
    float* vb    = (float*)carve((size_t)1576 * 768 * 4);
    float* gateb = (float*)carve((size_t)NPAIRS * 4);
    float* plg   = (float*)carve((size_t)3 * NPAIRS * 4);

    hipLaunchKernelGGL(prep_weights, dim3(756), dim3(256), 0, stream,
                       Wq, Wk, Wv, Wt, Wi, W1, W5s, W1Bs);
    hipLaunchKernelGGL(proj_kernel, dim3(8, 24), dim3(256), 0, stream,
                       text, 512, W5s, 0, bt, bq, (const float*)nullptr,
                       te, qb, (float*)nullptr);
    hipLaunchKernelGGL(proj_kernel, dim3(25, 36), dim3(256), 0, stream,
                       image, 1576, W5s, 2, bi, bk, bv,
                       ieb, kb, vb);
    hipLaunchKernelGGL(gate_gemm, dim3(MTILES * 3), dim3(512), 0, stream,
                       te, ieb, W1Bs, b1, W2, plg);
    hipLaunchKernelGGL(gate_fin, dim3((NPAIRS + 255) / 256), dim3(256), 0, stream,
                       plg, b2, gateb);
    hipLaunchKernelGGL(attn_kernel, dim3(BATCH * NHEADS * 4), dim3(256), 0, stream,
                       qb, kb, vb, gateb, out);
}

// Round 13
// 353.613 us; speedup vs baseline: 1.1417x; 1.1417x over previous
//
#include <hip/hip_runtime.h>
#include <stdint.h>

#define HD 768
#define NHEADS 12
#define DHEAD 64
#define BATCH 8
#define TLEN 64
#define ILEN 197
#define NPAIRS 100864   // = 394*256 exactly
#define MTILES 394

typedef __attribute__((ext_vector_type(8))) short short8;
typedef __attribute__((ext_vector_type(4))) float f32x4;

__device__ __forceinline__ short f2bf(float x) {
    union { float f; uint32_t u; } v; v.f = x;
    uint32_t r = v.u + 0x7FFFu + ((v.u >> 16) & 1u);
    return (short)(r >> 16);
}
__device__ __forceinline__ float bf2f(short s) {
    union { uint32_t u; float f; } v; v.u = ((uint32_t)(unsigned short)s) << 16;
    return v.f;
}
__device__ __forceinline__ uint32_t cvtpk(float lo, float hi) {
    uint32_t r;
    asm("v_cvt_pk_bf16_f32 %0, %1, %2" : "=v"(r) : "v"(lo), "v"(hi));
    return r;
}
__device__ __forceinline__ void gll16(const void* g, void* l) {
    __builtin_amdgcn_global_load_lds(
        (const __attribute__((address_space(1))) unsigned int*)g,
        (__attribute__((address_space(3))) unsigned int*)l, 16, 0, 0);
}

// ---------------------------------------------------------------------------
// Prep: W5s proj chunks (unchanged) + W1Bs gate-GEMM B chunks, NEW ks-major
// layout: chunk (pn,kt) = 32 KB, ks-block (16 KB) contiguous:
//   byte = ks*16384 + col*64 + ((g*16) ^ (((col>>1)&3)<<4)), g = k_in_slice/8.
// 2-way (free) bank pattern on ds_read_b128; gll16-linear per ks-block.
// ---------------------------------------------------------------------------
__global__ __launch_bounds__(256) void prep_weights(
    const float* __restrict__ Wq, const float* __restrict__ Wk,
    const float* __restrict__ Wv, const float* __restrict__ Wt,
    const float* __restrict__ Wi, const float* __restrict__ W1,
    short* __restrict__ W5s, short* __restrict__ W1Bs)
{
    __shared__ float tile[64][65];
    int bx = blockIdx.x;
    int tid = threadIdx.x;
    if (bx >= 720) {
        int idx = bx - 720;            // 0..35
        int pn = idx / 12, kt = idx - pn * 12;
        int c = tid;                   // col 0..255
        int j = pn * 256 + c;
        char* chunk = (char*)W1Bs + (size_t)idx * 32768;
        int f = (c >> 1) & 3;
#pragma unroll
        for (int ks = 0; ks < 2; ++ks) {
            char* dst = chunk + ks * 16384 + c * 64;
#pragma unroll
            for (int g = 0; g < 4; ++g) {
                short8 o;
#pragma unroll
                for (int e = 0; e < 8; ++e)
                    o[e] = f2bf(W1[(size_t)(kt * 64 + ks * 32 + g * 8 + e) * HD + j]);
                *(short8*)(dst + ((g * 16) ^ (f << 4))) = o;
            }
        }
        return;
    }
    int seg = bx / 144, ti = bx - seg * 144;
    const float* src = (seg == 0) ? Wt : (seg == 1) ? Wq : (seg == 2) ? Wi
                     : (seg == 3) ? Wk : Wv;
    int kt = ti / 12, ntile = ti - kt * 12;
#pragma unroll
    for (int pass = 0; pass < 16; ++pass) {
        int idx = pass * 256 + tid;
        int kk = idx >> 6, nn = idx & 63;
        tile[kk][nn] = src[(size_t)(kt * 64 + kk) * HD + ntile * 64 + nn];
    }
    __syncthreads();
    size_t base = ((size_t)(seg * 12 + ntile) * 12 + kt) * 8192;
#pragma unroll
    for (int pass = 0; pass < 16; ++pass) {
        int idx = pass * 256 + tid;
        int col = idx >> 6, kloc = idx & 63;
        float x = tile[kloc][col];
        short h = f2bf(x);
        short lw = f2bf(x - bf2f(h));
        int sidx = (col * 64 + kloc) ^ ((col & 7) << 3);
        W5s[base + sidx] = h;
        W5s[base + 4096 + sidx] = lw;
    }
}

// ---------------------------------------------------------------------------
// Projection GEMM (hi/lo bf16 split, near-fp32) — unchanged from R3.
// ---------------------------------------------------------------------------
__global__ __launch_bounds__(256, 1) void proj_kernel(
    const float* __restrict__ X, int M,
    const short* __restrict__ W5s, int segbase,
    const float* __restrict__ bias0, const float* __restrict__ bias1,
    const float* __restrict__ bias2,
    float* __restrict__ out0, float* __restrict__ out1, float* __restrict__ out2)
{
    __shared__ __align__(16) short Bs[2][8192];
    int tid = threadIdx.x;
    int l = tid & 63, w = tid >> 6;
    int lo = l & 15, grp = l >> 4;
    int y = blockIdx.y;
    int segl = y / 12, ntile = y - segl * 12;
    int seg = segbase + segl;
    const char* wsrc = (const char*)W5s + (size_t)((seg * 12 + ntile) * 12) * 16384;
    {
        const char* s = wsrc + w * 4096 + l * 16;
        char* d = (char*)&Bs[0][0] + w * 4096;
        gll16(s, d); gll16(s + 1024, d + 1024);
        gll16(s + 2048, d + 2048); gll16(s + 3072, d + 3072);
    }
    int arow = blockIdx.x * 64 + w * 16 + lo;
    bool aok = arow < M;
    const float* xrow = X + (size_t)(aok ? arow : 0) * HD;
    short8 ah[24], al[24];
#pragma unroll
    for (int kc = 0; kc < 24; ++kc) {
        int kb = kc * 32 + grp * 8;
        float4 xa = {0.f, 0.f, 0.f, 0.f}, xb = {0.f, 0.f, 0.f, 0.f};
        if (aok) { xa = *(const float4*)(xrow + kb); xb = *(const float4*)(xrow + kb + 4); }
        float xs[8] = {xa.x, xa.y, xa.z, xa.w, xb.x, xb.y, xb.z, xb.w};
#pragma unroll
        for (int e = 0; e < 8; ++e) {
            short hh = f2bf(xs[e]);
            ah[kc][e] = hh;
            al[kc][e] = f2bf(xs[e] - bf2f(hh));
        }
    }
    __syncthreads();

    f32x4 acc[4];
    f32x4 z4 = {0.f, 0.f, 0.f, 0.f};
#pragma unroll
    for (int js = 0; js < 4; ++js) acc[js] = z4;

#pragma unroll
    for (int kk = 0; kk < 12; ++kk) {
        const short* buf = &Bs[kk & 1][0];
        if (kk < 11) {
            const char* s = wsrc + (size_t)(kk + 1) * 16384 + w * 4096 + l * 16;
            char* d = (char*)&Bs[(kk + 1) & 1][0] + w * 4096;
            gll16(s, d); gll16(s + 1024, d + 1024);
            gll16(s + 2048, d + 2048); gll16(s + 3072, d + 3072);
            asm volatile("s_waitcnt vmcnt(4)" ::: "memory");
        } else {
            asm volatile("s_waitcnt vmcnt(0)" ::: "memory");
        }
        __builtin_amdgcn_s_barrier();
        asm volatile("" ::: "memory");
#pragma unroll
        for (int js = 0; js < 4; ++js) {
            int col = js * 16 + lo;
            int base = col * 64;
            int sw = (col & 7) << 3;
#pragma unroll
            for (int kcl = 0; kcl < 2; ++kcl) {
                int idx = (base + kcl * 32 + grp * 8) ^ sw;
                short8 bh = *(const short8*)&buf[idx];
                short8 bl = *(const short8*)&buf[4096 + idx];
                int kc = kk * 2 + kcl;
                acc[js] = __builtin_amdgcn_mfma_f32_16x16x32_bf16(ah[kc], bh, acc[js], 0, 0, 0);
                acc[js] = __builtin_amdgcn_mfma_f32_16x16x32_bf16(ah[kc], bl, acc[js], 0, 0, 0);
                acc[js] = __builtin_amdgcn_mfma_f32_16x16x32_bf16(al[kc], bh, acc[js], 0, 0, 0);
            }
        }
        asm volatile("s_waitcnt lgkmcnt(0)" ::: "memory");
        __builtin_amdgcn_s_barrier();
        asm volatile("" ::: "memory");
    }
    const float* bp = (segl == 0) ? bias0 : (segl == 1) ? bias1 : bias2;
    float* op = (segl == 0) ? out0 : (segl == 1) ? out1 : out2;
#pragma unroll
    for (int js = 0; js < 4; ++js) {
        int cc = ntile * 64 + js * 16 + lo;
        float bvv = bp[cc];
#pragma unroll
        for (int r = 0; r < 4; ++r) {
            int orow = blockIdx.x * 64 + w * 16 + grp * 4 + r;
            if (orow < M) op[(size_t)orow * HD + cc] = acc[js][r] + bvv;
        }
    }
}

// ---------------------------------------------------------------------------
// build_a v2: COALESCED construction of A = bf16(te⊙ie) in the new ks-major
// layout. Per (m_l, kt) block: cooperative coalesced loads of the 64-k slices
// of all 256 rows into LDS (stride-68 rows: 2-way bank = free), then thread t
// transposes row t: multiply, cvt_pk, swizzled coalesced global write.
// Kills the per-lane row gather (~40-64 lines/instr -> 16 lines/instr).
// ---------------------------------------------------------------------------
__global__ __launch_bounds__(256) void build_a(
    const float* __restrict__ te, const float* __restrict__ ie,
    short* __restrict__ As, int mstart)
{
    __shared__ float raw[2][256][68];   // [0]=ie, [1]=te slices (+pad)
    __shared__ int offs[2][256];
    int bx = blockIdx.x;
    int m_l = bx / 12, kt = bx - m_l * 12;
    int tid = threadIdx.x;
    {
        int p = (mstart + m_l) * 256 + tid;
        int b = p / 12608; int rr = p - b * 12608;
        int t = rr / 197;  int i = rr - t * 197;
        offs[0][tid] = (b * 197 + i) * HD + kt * 64;
        offs[1][tid] = (b * 64 + t) * HD + kt * 64;
    }
    __syncthreads();
    for (int it = 0; it < 16; ++it) {
        int idx = it * 256 + tid;
        int row = idx >> 4, f4 = idx & 15;
        *(float4*)&raw[0][row][f4 * 4] = *(const float4*)(ie + offs[0][row] + f4 * 4);
        *(float4*)&raw[1][row][f4 * 4] = *(const float4*)(te + offs[1][row] + f4 * 4);
    }
    __syncthreads();
    char* chunk = (char*)As + (size_t)(m_l * 12 + kt) * 32768;
    int f = (tid >> 1) & 3;
#pragma unroll
    for (int ks = 0; ks < 2; ++ks) {
        uint32_t o[16];
#pragma unroll
        for (int g = 0; g < 8; ++g) {
            float4 x  = *(const float4*)&raw[0][tid][ks * 32 + g * 4];
            float4 t4 = *(const float4*)&raw[1][tid][ks * 32 + g * 4];
            o[g * 2]     = cvtpk(x.x * t4.x, x.y * t4.y);
            o[g * 2 + 1] = cvtpk(x.z * t4.z, x.w * t4.w);
        }
        char* dst = chunk + ks * 16384 + tid * 64;
#pragma unroll
        for (int g2 = 0; g2 < 4; ++g2) {
            uint4 v = {o[4 * g2], o[4 * g2 + 1], o[4 * g2 + 2], o[4 * g2 + 3]};
            *(uint4*)(dst + ((g2 * 16) ^ (f << 4))) = v;
        }
    }
}

// ---------------------------------------------------------------------------
// gate_gemm: 256x256 tile, BK=64, 8 waves (2Mx4N), per-wave 128x64 out.
// R13: m201-style 4-phase/K-tile schedule with COUNTED vmcnt (T3+T4):
// phases (ks0,rt0-3),(ks0,rt4-7),(ks1,rt0-3),(ks1,rt4-7); each phase =
// {ds_read 4-8 b128 || stage one 16KB ks-block (2 gll16) -> barrier ->
//  lgkmcnt(0)+sched_barrier -> setprio(1) 16 MFMA setprio(0) -> [wait] ->
//  barrier}. Waits: vmcnt(4) end of phase 2 (covers B-ks1 of current tile),
// vmcnt(2) end of phase 4 (tile boundary) — never 0 until the tail.
// Stage order per tile kt (targets kt+1): A-ks0, A-ks1, B-ks0, B-ks1.
// FIFO check: boundary vmcnt(2) leaves only B-ks1(kt+1) in flight; phase-2
// vmcnt(4) retires it before phase 3 reads it. WAR: stage target buffer's
// last reads completed before the previous tile's end barrier.
// ---------------------------------------------------------------------------
__global__ __launch_bounds__(512, 2) void gate_gemm(
    const short* __restrict__ As, const short* __restrict__ W1Bs,
    const float* __restrict__ b1, const float* __restrict__ W2,
    float* __restrict__ plg, int mstart)
{
    __shared__ __align__(16) char lds[131072];   // A dbuf [0,64K), B dbuf [64K,128K)
    int tid = threadIdx.x;
    int lane = tid & 63, wid = tid >> 6;
    int lo = lane & 15, grp = lane >> 4;
    int wr = wid >> 2, wc = wid & 3;
    // bijective XCD swizzle (m204)
    int bx0 = blockIdx.x;
    int nwg = gridDim.x;
    int qq = nwg >> 3, rr8 = nwg & 7;
    int xcd = bx0 & 7;
    int logical = (xcd < rr8 ? xcd * (qq + 1) : rr8 * (qq + 1) + (xcd - rr8) * qq)
                + (bx0 >> 3);
    int m_l = logical / 3, pn = logical - m_l * 3;

    const char* Ag = (const char*)As + (size_t)m_l * 12 * 32768;
    const char* Bg = (const char*)W1Bs + (size_t)pn * 12 * 32768;

    // stage one 16KB ks-block of tile t into parity (t&1)
    auto stageA = [&](int t, int ks) {
        const char* s = Ag + (size_t)t * 32768 + ks * 16384 + tid * 16;
        char* d = lds + (t & 1) * 32768 + ks * 16384 + tid * 16;
        gll16(s, d); gll16(s + 8192, d + 8192);
    };
    auto stageB = [&](int t, int ks) {
        const char* s = Bg + (size_t)t * 32768 + ks * 16384 + tid * 16;
        char* d = lds + 65536 + (t & 1) * 32768 + ks * 16384 + tid * 16;
        gll16(s, d); gll16(s + 8192, d + 8192);
    };
    // prologue: tile 0's four ks-blocks, in canonical order
    stageA(0, 0); stageA(0, 1); stageB(0, 0); stageB(0, 1);
    asm volatile("s_waitcnt vmcnt(2)" ::: "memory");
    __builtin_amdgcn_s_barrier();
    asm volatile("" ::: "memory");

    f32x4 acc[8][4];
    f32x4 z4 = {0.f, 0.f, 0.f, 0.f};
#pragma unroll
    for (int rt = 0; rt < 8; ++rt)
#pragma unroll
        for (int ct = 0; ct < 4; ++ct) acc[rt][ct] = z4;

    for (int kt = 0; kt < 12; ++kt) {
        int par = kt & 1;
        int aoff = par * 32768;
        int boff = 65536 + par * 32768;
        bool more = kt < 11;
        short8 bfr[4], af[4];

#pragma unroll
        for (int ph = 0; ph < 4; ++ph) {
            int ksp = ph >> 1;          // 0,0,1,1
            int rh  = ph & 1;           // 0,1,0,1
            // ---- ds reads for this phase ----
            if (rh == 0) {              // new ks: read B frags
#pragma unroll
                for (int ct = 0; ct < 4; ++ct) {
                    int c = wc * 64 + ct * 16 + lo;
                    bfr[ct] = *(const short8*)(lds + boff + ksp * 16384 + c * 64
                                + ((grp * 16) ^ (((c >> 1) & 3) << 4)));
                }
            }
#pragma unroll
            for (int j = 0; j < 4; ++j) {
                int r = wr * 128 + (rh * 4 + j) * 16 + lo;
                af[j] = *(const short8*)(lds + aoff + ksp * 16384 + r * 64
                            + ((grp * 16) ^ (((r >> 1) & 3) << 4)));
            }
            // ---- stage one ks-block of tile kt+1 ----
            if (more) {
                if (ph == 0)      stageA(kt + 1, 0);
                else if (ph == 1) stageA(kt + 1, 1);
                else if (ph == 2) stageB(kt + 1, 0);
                else              stageB(kt + 1, 1);
            }
            __builtin_amdgcn_s_barrier();
            asm volatile("s_waitcnt lgkmcnt(0)" ::: "memory");
            __builtin_amdgcn_sched_barrier(0);
            __builtin_amdgcn_s_setprio(1);
#pragma unroll
            for (int j = 0; j < 4; ++j)
#pragma unroll
                for (int ct = 0; ct < 4; ++ct)
                    acc[rh * 4 + j][ct] = __builtin_amdgcn_mfma_f32_16x16x32_bf16(
                        af[j], bfr[ct], acc[rh * 4 + j][ct], 0, 0, 0);
            __builtin_amdgcn_s_setprio(0);
            // ---- counted waits: never drain mid-pipeline ----
            if (ph == 1) {
                if (more) asm volatile("s_waitcnt vmcnt(4)" ::: "memory");
                else      asm volatile("s_waitcnt vmcnt(0)" ::: "memory");
            } else if (ph == 3) {
                if (more) asm volatile("s_waitcnt vmcnt(2)" ::: "memory");
                else      asm volatile("s_waitcnt vmcnt(0)" ::: "memory");
            }
            __builtin_amdgcn_s_barrier();
            asm volatile("" ::: "memory");
        }
    }

    // epilogue: h = relu(acc + b1); per-wave partial logit over its 64 cols
    float b1v[4], w2v[4];
#pragma unroll
    for (int ct = 0; ct < 4; ++ct) {
        int j = pn * 256 + wc * 64 + ct * 16 + lo;
        b1v[ct] = b1[j]; w2v[ct] = W2[j];
    }
    float pl[8][4];
#pragma unroll
    for (int rt = 0; rt < 8; ++rt)
#pragma unroll
        for (int r = 0; r < 4; ++r) {
            float s = 0.f;
#pragma unroll
            for (int ct = 0; ct < 4; ++ct)
                s += fmaxf(acc[rt][ct][r] + b1v[ct], 0.f) * w2v[ct];
            pl[rt][r] = s;
        }
#pragma unroll
    for (int msk = 1; msk <= 8; msk <<= 1)
#pragma unroll
        for (int rt = 0; rt < 8; ++rt)
#pragma unroll
            for (int r = 0; r < 4; ++r)
                pl[rt][r] += __shfl_xor(pl[rt][r], msk);

    // reduce the 4 wc-wave partials through (now dead) LDS
    __syncthreads();
    float* red = (float*)lds;                       // [8 wid][128 row]
    if (lo == 0) {
#pragma unroll
        for (int rt = 0; rt < 8; ++rt)
#pragma unroll
            for (int r = 0; r < 4; ++r)
                red[wid * 128 + rt * 16 + grp * 4 + r] = pl[rt][r];
    }
    __syncthreads();
    if (tid < 256) {
        int wr_ = tid >> 7, rl = tid & 127;
        float s = red[(wr_ * 4 + 0) * 128 + rl] + red[(wr_ * 4 + 1) * 128 + rl]
                + red[(wr_ * 4 + 2) * 128 + rl] + red[(wr_ * 4 + 3) * 128 + rl];
        plg[(size_t)pn * NPAIRS + (size_t)(mstart + m_l) * 256 + tid] = s;
    }
}

// ---------------------------------------------------------------------------
__global__ __launch_bounds__(256) void gate_fin(
    const float* __restrict__ plg, const float* __restrict__ b2,
    float* __restrict__ gateb)
{
    int idx = blockIdx.x * 256 + threadIdx.x;
    if (idx < NPAIRS) {
        float s = plg[idx] + plg[NPAIRS + idx] + plg[2 * NPAIRS + idx] + b2[0];
        gateb[idx] = 1.f / (1.f + __expf(-s));
    }
}

// ---------------------------------------------------------------------------
// Cross-attention, fp32 VALU. Grid = (b,h,t-quarter) = 384 blocks.
// R9 structure: softmax rows into p_s[w][i][4], single PV pass (1x v reads).
// ---------------------------------------------------------------------------
__global__ __launch_bounds__(256) void attn_kernel(
    const float* __restrict__ q, const float* __restrict__ k,
    const float* __restrict__ v, const float* __restrict__ gate,
    float* __restrict__ out)
{
    __shared__ float k_s[ILEN * 65];
    __shared__ float p_s[4][ILEN][4];   // [wave][i][tt]
    int bx = blockIdx.x;
    int tq = bx & 3;
    int h = (bx >> 2) % NHEADS;
    int b = bx / (4 * NHEADS);
    int tid = threadIdx.x;
    for (int idx = tid; idx < ILEN * DHEAD; idx += 256) {
        int i = idx >> 6, d = idx & 63;
        k_s[i * 65 + d] = k[(size_t)(b * ILEN + i) * HD + h * DHEAD + d];
    }
    __syncthreads();

    int l = tid & 63, w = tid >> 6;
    int tbase = tq * 16 + w * 4;

    for (int tt = 0; tt < 4; ++tt) {
        int t = tbase + tt;
        float qv = q[(size_t)(b * 64 + t) * HD + h * DHEAD + l];
        float s0 = 0.f, s1 = 0.f, s2 = 0.f, s3 = 0.f;
        int i0 = l, i1 = 64 + l, i2 = 128 + l;
        int i3c = (192 + l < ILEN) ? 192 + l : 0;
        for (int d = 0; d < 64; ++d) {
            float qd = __shfl(qv, d);
            s0 += qd * k_s[i0 * 65 + d];
            s1 += qd * k_s[i1 * 65 + d];
            s2 += qd * k_s[i2 * 65 + d];
            s3 += qd * k_s[i3c * 65 + d];
        }
        float sc[4] = {s0, s1, s2, s3};
        float m = -3.0e38f;
#pragma unroll
        for (int rep = 0; rep < 4; ++rep) {
            int i = rep * 64 + l;
            sc[rep] = (i < ILEN) ? sc[rep] * 0.125f : -3.0e38f;
            m = fmaxf(m, sc[rep]);
        }
        for (int mask = 32; mask >= 1; mask >>= 1) m = fmaxf(m, __shfl_xor(m, mask));
        float sum = 0.f;
#pragma unroll
        for (int rep = 0; rep < 4; ++rep) {
            float e = __expf(sc[rep] - m);
            sc[rep] = e;
            sum += e;
        }
        for (int mask = 32; mask >= 1; mask >>= 1) sum += __shfl_xor(sum, mask);
        float inv = 1.f / sum;
        const float* grow = gate + (size_t)(b * 64 + t) * ILEN;
#pragma unroll
        for (int rep = 0; rep < 4; ++rep) {
            int i = rep * 64 + l;
            if (i < ILEN) p_s[w][i][tt] = sc[rep] * inv * grow[i];
        }
    }
    // same wave writes & reads p_s -> no barrier needed

    float ctx[4] = {0.f, 0.f, 0.f, 0.f};
    const float* vbase = v + (size_t)(b * ILEN) * HD + h * DHEAD + l;
#pragma unroll 4
    for (int i = 0; i < ILEN; ++i) {
        float vv = vbase[(size_t)i * HD];
        float4 p4 = *(const float4*)&p_s[w][i][0];
        ctx[0] += p4.x * vv;
        ctx[1] += p4.y * vv;
        ctx[2] += p4.z * vv;
        ctx[3] += p4.w * vv;
    }
#pragma unroll
    for (int tt = 0; tt < 4; ++tt)
        out[(size_t)(b * 64 + tbase + tt) * HD + h * DHEAD + l] = ctx[tt];
}

// ---------------------------------------------------------------------------
extern "C" void kernel_launch(void* const* d_in, const int* in_sizes, int n_in,
                              void* d_out, int out_size, void* d_ws, size_t ws_size,
                              hipStream_t stream)
{
    const float* text  = (const float*)d_in[0];
    const float* image = (const float*)d_in[1];
    const float* Wq = (const float*)d_in[2];
    const float* bq = (const float*)d_in[3];
    const float* Wk = (const float*)d_in[4];
    const float* bk = (const float*)d_in[5];
    const float* Wv = (const float*)d_in[6];
    const float* bv = (const float*)d_in[7];
    const float* Wt = (const float*)d_in[8];
    const float* bt = (const float*)d_in[9];
    const float* Wi = (const float*)d_in[10];
    const float* bi = (const float*)d_in[11];
    const float* W1 = (const float*)d_in[12];
    const float* b1 = (const float*)d_in[13];
    const float* W2 = (const float*)d_in[14];
    const float* b2 = (const float*)d_in[15];
    float* out = (float*)d_out;

    char* ws = (char*)d_ws;
    size_t off = 0;
    auto carve = [&](size_t bytes) -> void* {
        void* p = (void*)(ws + off);
        off += (bytes + 255) & ~(size_t)255;
        return p;
    };
    short* W5s  = (short*)carve((size_t)5 * 144 * 8192 * 2);   // 11.8 MB
    short* W1Bs = (short*)carve((size_t)36 * 32768);           // 1.18 MB
    float* te    = (float*)carve((size_t)512 * 768 * 4);
    float* qb    = (float*)carve((size_t)512 * 768 * 4);
    float* ieb   = (float*)carve((size_t)1576 * 768 * 4);
    float* kb    = (float*)carve((size_t)1576 * 768 * 4);
    float* vb    = (float*)carve((size_t)1576 * 768 * 4);
    float* gateb = (float*)carve((size_t)NPAIRS * 4);
    float* plg   = (float*)carve((size_t)3 * NPAIRS * 4);

    // A buffer: as many M-tiles as workspace allows (stripe loop)
    size_t per_m = (size_t)12 * 32768;                          // 384 KB per M-tile
    size_t avail = (ws_size > off) ? (ws_size - off) : 0;
    int stripe = (int)(avail / per_m);
    if (stripe > MTILES) stripe = MTILES;
    if (stripe < 1) stripe = 1;
    short* As = (short*)(ws + off);
    int nst = (MTILES + stripe - 1) / stripe;

    hipLaunchKernelGGL(prep_weights, dim3(756), dim3(256), 0, stream,
                       Wq, Wk, Wv, Wt, Wi, W1, W5s, W1Bs);
    hipLaunchKernelGGL(proj_kernel, dim3(8, 24), dim3(256), 0, stream,
                       text, 512, W5s, 0, bt, bq, (const float*)nullptr,
                       te, qb, (float*)nullptr);
    hipLaunchKernelGGL(proj_kernel, dim3(25, 36), dim3(256), 0, stream,
                       image, 1576, W5s, 2, bi, bk, bv,
                       ieb, kb, vb);
    for (int s = 0; s < nst; ++s) {
        int m0 = s * stripe;
        int mc = (MTILES - m0 < stripe) ? (MTILES - m0) : stripe;
        hipLaunchKernelGGL(build_a, dim3(mc * 12), dim3(256), 0, stream,
                           te, ieb, As, m0);
        hipLaunchKernelGGL(gate_gemm, dim3(mc * 3), dim3(512), 0, stream,
                           As, W1Bs, b1, W2, plg, m0);
    }
    hipLaunchKernelGGL(gate_fin, dim3((NPAIRS + 255) / 256), dim3(256), 0, stream,
                       plg, b2, gateb);
    hipLaunchKernelGGL(attn_kernel, dim3(BATCH * NHEADS * 4), dim3(256), 0, stream,
                       qb, kb, vb, gateb, out);
}

// Round 14
// 336.037 us; speedup vs baseline: 1.2014x; 1.0523x over previous
//
#include <hip/hip_runtime.h>
#include <stdint.h>

#define HD 768
#define NHEADS 12
#define DHEAD 64
#define BATCH 8
#define TLEN 64
#define ILEN 197
#define NPAIRS 100864   // = 394*256 exactly
#define MTILES 394

typedef __attribute__((ext_vector_type(8))) short short8;
typedef __attribute__((ext_vector_type(4))) float f32x4;

__device__ __forceinline__ short f2bf(float x) {
    union { float f; uint32_t u; } v; v.f = x;
    uint32_t r = v.u + 0x7FFFu + ((v.u >> 16) & 1u);
    return (short)(r >> 16);
}
__device__ __forceinline__ float bf2f(short s) {
    union { uint32_t u; float f; } v; v.u = ((uint32_t)(unsigned short)s) << 16;
    return v.f;
}
__device__ __forceinline__ uint32_t cvtpk(float lo, float hi) {
    uint32_t r;
    asm("v_cvt_pk_bf16_f32 %0, %1, %2" : "=v"(r) : "v"(lo), "v"(hi));
    return r;
}
__device__ __forceinline__ void gll16(const void* g, void* l) {
    __builtin_amdgcn_global_load_lds(
        (const __attribute__((address_space(1))) unsigned int*)g,
        (__attribute__((address_space(3))) unsigned int*)l, 16, 0, 0);
}

// ---------------------------------------------------------------------------
// Prep: W5s proj chunks (unchanged) + W1Bs gate-GEMM B chunks, ks-major
// layout (R13): chunk (pn,kt) = 32 KB, ks-block (16 KB) contiguous:
//   byte = ks*16384 + col*64 + ((g*16) ^ (((col>>1)&3)<<4)), g = k_in_slice/8.
// 2-way (free) bank pattern on ds_read_b128; gll16-linear per ks-block.
// ---------------------------------------------------------------------------
__global__ __launch_bounds__(256) void prep_weights(
    const float* __restrict__ Wq, const float* __restrict__ Wk,
    const float* __restrict__ Wv, const float* __restrict__ Wt,
    const float* __restrict__ Wi, const float* __restrict__ W1,
    short* __restrict__ W5s, short* __restrict__ W1Bs)
{
    __shared__ float tile[64][65];
    int bx = blockIdx.x;
    int tid = threadIdx.x;
    if (bx >= 720) {
        int idx = bx - 720;            // 0..35
        int pn = idx / 12, kt = idx - pn * 12;
        int c = tid;                   // col 0..255
        int j = pn * 256 + c;
        char* chunk = (char*)W1Bs + (size_t)idx * 32768;
        int f = (c >> 1) & 3;
#pragma unroll
        for (int ks = 0; ks < 2; ++ks) {
            char* dst = chunk + ks * 16384 + c * 64;
#pragma unroll
            for (int g = 0; g < 4; ++g) {
                short8 o;
#pragma unroll
                for (int e = 0; e < 8; ++e)
                    o[e] = f2bf(W1[(size_t)(kt * 64 + ks * 32 + g * 8 + e) * HD + j]);
                *(short8*)(dst + ((g * 16) ^ (f << 4))) = o;
            }
        }
        return;
    }
    int seg = bx / 144, ti = bx - seg * 144;
    const float* src = (seg == 0) ? Wt : (seg == 1) ? Wq : (seg == 2) ? Wi
                     : (seg == 3) ? Wk : Wv;
    int kt = ti / 12, ntile = ti - kt * 12;
#pragma unroll
    for (int pass = 0; pass < 16; ++pass) {
        int idx = pass * 256 + tid;
        int kk = idx >> 6, nn = idx & 63;
        tile[kk][nn] = src[(size_t)(kt * 64 + kk) * HD + ntile * 64 + nn];
    }
    __syncthreads();
    size_t base = ((size_t)(seg * 12 + ntile) * 12 + kt) * 8192;
#pragma unroll
    for (int pass = 0; pass < 16; ++pass) {
        int idx = pass * 256 + tid;
        int col = idx >> 6, kloc = idx & 63;
        float x = tile[kloc][col];
        short h = f2bf(x);
        short lw = f2bf(x - bf2f(h));
        int sidx = (col * 64 + kloc) ^ ((col & 7) << 3);
        W5s[base + sidx] = h;
        W5s[base + 4096 + sidx] = lw;
    }
}

// ---------------------------------------------------------------------------
// Projection GEMM (hi/lo bf16 split, near-fp32) — unchanged from R3.
// ---------------------------------------------------------------------------
__global__ __launch_bounds__(256, 1) void proj_kernel(
    const float* __restrict__ X, int M,
    const short* __restrict__ W5s, int segbase,
    const float* __restrict__ bias0, const float* __restrict__ bias1,
    const float* __restrict__ bias2,
    float* __restrict__ out0, float* __restrict__ out1, float* __restrict__ out2)
{
    __shared__ __align__(16) short Bs[2][8192];
    int tid = threadIdx.x;
    int l = tid & 63, w = tid >> 6;
    int lo = l & 15, grp = l >> 4;
    int y = blockIdx.y;
    int segl = y / 12, ntile = y - segl * 12;
    int seg = segbase + segl;
    const char* wsrc = (const char*)W5s + (size_t)((seg * 12 + ntile) * 12) * 16384;
    {
        const char* s = wsrc + w * 4096 + l * 16;
        char* d = (char*)&Bs[0][0] + w * 4096;
        gll16(s, d); gll16(s + 1024, d + 1024);
        gll16(s + 2048, d + 2048); gll16(s + 3072, d + 3072);
    }
    int arow = blockIdx.x * 64 + w * 16 + lo;
    bool aok = arow < M;
    const float* xrow = X + (size_t)(aok ? arow : 0) * HD;
    short8 ah[24], al[24];
#pragma unroll
    for (int kc = 0; kc < 24; ++kc) {
        int kb = kc * 32 + grp * 8;
        float4 xa = {0.f, 0.f, 0.f, 0.f}, xb = {0.f, 0.f, 0.f, 0.f};
        if (aok) { xa = *(const float4*)(xrow + kb); xb = *(const float4*)(xrow + kb + 4); }
        float xs[8] = {xa.x, xa.y, xa.z, xa.w, xb.x, xb.y, xb.z, xb.w};
#pragma unroll
        for (int e = 0; e < 8; ++e) {
            short hh = f2bf(xs[e]);
            ah[kc][e] = hh;
            al[kc][e] = f2bf(xs[e] - bf2f(hh));
        }
    }
    __syncthreads();

    f32x4 acc[4];
    f32x4 z4 = {0.f, 0.f, 0.f, 0.f};
#pragma unroll
    for (int js = 0; js < 4; ++js) acc[js] = z4;

#pragma unroll
    for (int kk = 0; kk < 12; ++kk) {
        const short* buf = &Bs[kk & 1][0];
        if (kk < 11) {
            const char* s = wsrc + (size_t)(kk + 1) * 16384 + w * 4096 + l * 16;
            char* d = (char*)&Bs[(kk + 1) & 1][0] + w * 4096;
            gll16(s, d); gll16(s + 1024, d + 1024);
            gll16(s + 2048, d + 2048); gll16(s + 3072, d + 3072);
            asm volatile("s_waitcnt vmcnt(4)" ::: "memory");
        } else {
            asm volatile("s_waitcnt vmcnt(0)" ::: "memory");
        }
        __builtin_amdgcn_s_barrier();
        asm volatile("" ::: "memory");
#pragma unroll
        for (int js = 0; js < 4; ++js) {
            int col = js * 16 + lo;
            int base = col * 64;
            int sw = (col & 7) << 3;
#pragma unroll
            for (int kcl = 0; kcl < 2; ++kcl) {
                int idx = (base + kcl * 32 + grp * 8) ^ sw;
                short8 bh = *(const short8*)&buf[idx];
                short8 bl = *(const short8*)&buf[4096 + idx];
                int kc = kk * 2 + kcl;
                acc[js] = __builtin_amdgcn_mfma_f32_16x16x32_bf16(ah[kc], bh, acc[js], 0, 0, 0);
                acc[js] = __builtin_amdgcn_mfma_f32_16x16x32_bf16(ah[kc], bl, acc[js], 0, 0, 0);
                acc[js] = __builtin_amdgcn_mfma_f32_16x16x32_bf16(al[kc], bh, acc[js], 0, 0, 0);
            }
        }
        asm volatile("s_waitcnt lgkmcnt(0)" ::: "memory");
        __builtin_amdgcn_s_barrier();
        asm volatile("" ::: "memory");
    }
    const float* bp = (segl == 0) ? bias0 : (segl == 1) ? bias1 : bias2;
    float* op = (segl == 0) ? out0 : (segl == 1) ? out1 : out2;
#pragma unroll
    for (int js = 0; js < 4; ++js) {
        int cc = ntile * 64 + js * 16 + lo;
        float bvv = bp[cc];
#pragma unroll
        for (int r = 0; r < 4; ++r) {
            int orow = blockIdx.x * 64 + w * 16 + grp * 4 + r;
            if (orow < M) op[(size_t)orow * HD + cc] = acc[js][r] + bvv;
        }
    }
}

// ---------------------------------------------------------------------------
// gate_gemm: 256x256 tile, BK=64, 8 waves (2Mx4N), per-wave 128x64 out.
// R14 = R13 core + FUSED COALESCED A-construction (no build_a, no As buffer):
//  - te rows for the block (<=3 distinct) live in a 9 KB LDS table;
//  - per K-tile: 8 coalesced ie float4 loads/thread (lane->(row,f4): 4 rows x
//    256B contiguous per instr) issued at tile-top alongside B's 4 gll16;
//  - after ph3's MFMAs (covered vmcnt(0)): mul -> v_cvt_pk_bf16_f32 ->
//    swizzled ds_write_b64 into the next A buffer (write layout == phase
//    ds_read layout, verified); lgkmcnt(0) before the boundary barrier.
// launch_bounds(512,1): LDS (138 KB) caps at 1 block/CU anyway; removes the
// 128-arch-VGPR spill cliff for the 32 in-flight load regs.
// ---------------------------------------------------------------------------
__global__ __launch_bounds__(512, 1) void gate_gemm(
    const float* __restrict__ te, const float* __restrict__ ie,
    const short* __restrict__ W1Bs, const float* __restrict__ b1,
    const float* __restrict__ W2, float* __restrict__ plg)
{
    __shared__ __align__(16) char lds[131072];   // A dbuf [0,64K), B dbuf [64K,128K)
    __shared__ float te_s[3 * HD];               // up to 3 te rows
    __shared__ int ieoff[256];                   // ie elem offset | (slot<<24)
    int tid = threadIdx.x;
    int lane = tid & 63, wid = tid >> 6;
    int lo = lane & 15, grp = lane >> 4;
    int wr = wid >> 2, wc = wid & 3;
    // bijective XCD swizzle (m204)
    int bx0 = blockIdx.x;
    int nwg = gridDim.x;
    int qq = nwg >> 3, rr8 = nwg & 7;
    int xcd = bx0 & 7;
    int logical = (xcd < rr8 ? xcd * (qq + 1) : rr8 * (qq + 1) + (xcd - rr8) * qq)
                + (bx0 >> 3);
    int m_l = logical / 3, pn = logical - m_l * 3;

    const char* Bg = (const char*)W1Bs + (size_t)pn * 12 * 32768;
    int bt0 = (m_l * 256) / 197;

    // ---- prologue: row tables + te LDS table ----
    if (tid < 256) {
        int p = m_l * 256 + tid;
        int bt = p / 197;
        int i = p - bt * 197;
        int b = bt >> 6;
        ieoff[tid] = (b * 197 + i) * HD | ((bt - bt0) << 24);
    }
    for (int idx = tid; idx < 3 * HD; idx += 512) {
        int r = idx / HD;
        int bt = bt0 + r; if (bt > 511) bt = 511;
        te_s[idx] = te[(size_t)bt * HD + (idx - r * HD)];
    }
    __syncthreads();

    // construct A(t) into A-buffer `par` — direct (prologue only)
    auto constructA0 = [&](int t, int par) {
#pragma unroll
        for (int u = 0; u < 8; ++u) {
            int w = u * 512 + tid;
            int row = w >> 4, f4 = w & 15;
            int pk = ieoff[row];
            float4 x = *(const float4*)(ie + (pk & 0xFFFFFF) + t * 64 + f4 * 4);
            const float* tp = &te_s[(pk >> 24) * HD + t * 64 + f4 * 4];
            float4 tv = *(const float4*)tp;
            uint32_t o0 = cvtpk(x.x * tv.x, x.y * tv.y);
            uint32_t o1 = cvtpk(x.z * tv.z, x.w * tv.w);
            int ks = f4 >> 3, r7 = f4 & 7, g = r7 >> 1, half = r7 & 1;
            char* dst = lds + par * 32768 + ks * 16384 + row * 64
                      + ((g * 16) ^ (((row >> 1) & 3) << 4)) + half * 8;
            uint2 o = {o0, o1};
            *(uint2*)dst = o;
        }
    };
    constructA0(0, 0);
    {   // stage B(0) into parity 0
        const char* s = Bg + tid * 16;
        char* d = lds + 65536 + tid * 16;
        gll16(s, d); gll16(s + 8192, d + 8192);
        gll16(s + 16384, d + 16384); gll16(s + 24576, d + 24576);
    }
    asm volatile("s_waitcnt vmcnt(0) lgkmcnt(0)" ::: "memory");
    __builtin_amdgcn_s_barrier();
    asm volatile("" ::: "memory");

    f32x4 acc[8][4];
    f32x4 z4 = {0.f, 0.f, 0.f, 0.f};
#pragma unroll
    for (int rt = 0; rt < 8; ++rt)
#pragma unroll
        for (int ct = 0; ct < 4; ++ct) acc[rt][ct] = z4;

    for (int kt = 0; kt < 12; ++kt) {
        int par = kt & 1, npar = par ^ 1;
        int aoff = par * 32768;
        int boff = 65536 + par * 32768;
        bool more = kt < 11;

        // ---- tile-top: issue ie loads for A(kt+1) + B(kt+1) staging ----
        float4 xi[8];
        if (more) {
#pragma unroll
            for (int u = 0; u < 8; ++u) {
                int w = u * 512 + tid;
                int row = w >> 4, f4 = w & 15;
                int pk = ieoff[row];
                xi[u] = *(const float4*)(ie + (pk & 0xFFFFFF) + (kt + 1) * 64 + f4 * 4);
            }
            const char* s = Bg + (size_t)(kt + 1) * 32768 + tid * 16;
            char* d = lds + 65536 + npar * 32768 + tid * 16;
            gll16(s, d); gll16(s + 8192, d + 8192);
            gll16(s + 16384, d + 16384); gll16(s + 24576, d + 24576);
        }

        // ---- 4 MFMA phases on tile kt (R13 structure) ----
        short8 bfr[4], af[4];
#pragma unroll
        for (int ph = 0; ph < 4; ++ph) {
            int ksp = ph >> 1;          // 0,0,1,1
            int rh  = ph & 1;           // 0,1,0,1
            if (rh == 0) {
#pragma unroll
                for (int ct = 0; ct < 4; ++ct) {
                    int c = wc * 64 + ct * 16 + lo;
                    bfr[ct] = *(const short8*)(lds + boff + ksp * 16384 + c * 64
                                + ((grp * 16) ^ (((c >> 1) & 3) << 4)));
                }
            }
#pragma unroll
            for (int j = 0; j < 4; ++j) {
                int r = wr * 128 + (rh * 4 + j) * 16 + lo;
                af[j] = *(const short8*)(lds + aoff + ksp * 16384 + r * 64
                            + ((grp * 16) ^ (((r >> 1) & 3) << 4)));
            }
            __builtin_amdgcn_s_barrier();
            asm volatile("s_waitcnt lgkmcnt(0)" ::: "memory");
            __builtin_amdgcn_sched_barrier(0);
            __builtin_amdgcn_s_setprio(1);
#pragma unroll
            for (int j = 0; j < 4; ++j)
#pragma unroll
                for (int ct = 0; ct < 4; ++ct)
                    acc[rh * 4 + j][ct] = __builtin_amdgcn_mfma_f32_16x16x32_bf16(
                        af[j], bfr[ct], acc[rh * 4 + j][ct], 0, 0, 0);
            __builtin_amdgcn_s_setprio(0);
            if (ph < 3) {
                __builtin_amdgcn_s_barrier();
                asm volatile("" ::: "memory");
            }
        }

        // ---- tile-tail: consume ie loads -> construct A(kt+1) into npar ----
        if (more) {
            asm volatile("s_waitcnt vmcnt(0)" ::: "memory");   // covered by 4 phases
#pragma unroll
            for (int u = 0; u < 8; ++u) {
                int w = u * 512 + tid;
                int row = w >> 4, f4 = w & 15;
                int pk = ieoff[row];
                const float* tp = &te_s[(pk >> 24) * HD + (kt + 1) * 64 + f4 * 4];
                float4 tv = *(const float4*)tp;
                float4 x = xi[u];
                uint32_t o0 = cvtpk(x.x * tv.x, x.y * tv.y);
                uint32_t o1 = cvtpk(x.z * tv.z, x.w * tv.w);
                int ks = f4 >> 3, r7 = f4 & 7, g = r7 >> 1, half = r7 & 1;
                char* dst = lds + npar * 32768 + ks * 16384 + row * 64
                          + ((g * 16) ^ (((row >> 1) & 3) << 4)) + half * 8;
                uint2 o = {o0, o1};
                *(uint2*)dst = o;
            }
        } else {
            asm volatile("s_waitcnt vmcnt(0)" ::: "memory");
        }
        asm volatile("s_waitcnt lgkmcnt(0)" ::: "memory");
        __builtin_amdgcn_s_barrier();
        asm volatile("" ::: "memory");
    }

    // epilogue: h = relu(acc + b1); per-wave partial logit over its 64 cols
    float b1v[4], w2v[4];
#pragma unroll
    for (int ct = 0; ct < 4; ++ct) {
        int j = pn * 256 + wc * 64 + ct * 16 + lo;
        b1v[ct] = b1[j]; w2v[ct] = W2[j];
    }
    float pl[8][4];
#pragma unroll
    for (int rt = 0; rt < 8; ++rt)
#pragma unroll
        for (int r = 0; r < 4; ++r) {
            float s = 0.f;
#pragma unroll
            for (int ct = 0; ct < 4; ++ct)
                s += fmaxf(acc[rt][ct][r] + b1v[ct], 0.f) * w2v[ct];
            pl[rt][r] = s;
        }
#pragma unroll
    for (int msk = 1; msk <= 8; msk <<= 1)
#pragma unroll
        for (int rt = 0; rt < 8; ++rt)
#pragma unroll
            for (int r = 0; r < 4; ++r)
                pl[rt][r] += __shfl_xor(pl[rt][r], msk);

    // reduce the 4 wc-wave partials through (now dead) LDS
    __syncthreads();
    float* red = (float*)lds;                       // [8 wid][128 row]
    if (lo == 0) {
#pragma unroll
        for (int rt = 0; rt < 8; ++rt)
#pragma unroll
            for (int r = 0; r < 4; ++r)
                red[wid * 128 + rt * 16 + grp * 4 + r] = pl[rt][r];
    }
    __syncthreads();
    if (tid < 256) {
        int wr_ = tid >> 7, rl = tid & 127;
        float s = red[(wr_ * 4 + 0) * 128 + rl] + red[(wr_ * 4 + 1) * 128 + rl]
                + red[(wr_ * 4 + 2) * 128 + rl] + red[(wr_ * 4 + 3) * 128 + rl];
        plg[(size_t)pn * NPAIRS + (size_t)m_l * 256 + tid] = s;
    }
}

// ---------------------------------------------------------------------------
__global__ __launch_bounds__(256) void gate_fin(
    const float* __restrict__ plg, const float* __restrict__ b2,
    float* __restrict__ gateb)
{
    int idx = blockIdx.x * 256 + threadIdx.x;
    if (idx < NPAIRS) {
        float s = plg[idx] + plg[NPAIRS + idx] + plg[2 * NPAIRS + idx] + b2[0];
        gateb[idx] = 1.f / (1.f + __expf(-s));
    }
}

// ---------------------------------------------------------------------------
// Cross-attention, fp32 VALU. Grid = (b,h,t-quarter) = 384 blocks.
// R9 structure: softmax rows into p_s[w][i][4], single PV pass (1x v reads).
// ---------------------------------------------------------------------------
__global__ __launch_bounds__(256) void attn_kernel(
    const float* __restrict__ q, const float* __restrict__ k,
    const float* __restrict__ v, const float* __restrict__ gate,
    float* __restrict__ out)
{
    __shared__ float k_s[ILEN * 65];
    __shared__ float p_s[4][ILEN][4];   // [wave][i][tt]
    int bx = blockIdx.x;
    int tq = bx & 3;
    int h = (bx >> 2) % NHEADS;
    int b = bx / (4 * NHEADS);
    int tid = threadIdx.x;
    for (int idx = tid; idx < ILEN * DHEAD; idx += 256) {
        int i = idx >> 6, d = idx & 63;
        k_s[i * 65 + d] = k[(size_t)(b * ILEN + i) * HD + h * DHEAD + d];
    }
    __syncthreads();

    int l = tid & 63, w = tid >> 6;
    int tbase = tq * 16 + w * 4;

    for (int tt = 0; tt < 4; ++tt) {
        int t = tbase + tt;
        float qv = q[(size_t)(b * 64 + t) * HD + h * DHEAD + l];
        float s0 = 0.f, s1 = 0.f, s2 = 0.f, s3 = 0.f;
        int i0 = l, i1 = 64 + l, i2 = 128 + l;
        int i3c = (192 + l < ILEN) ? 192 + l : 0;
        for (int d = 0; d < 64; ++d) {
            float qd = __shfl(qv, d);
            s0 += qd * k_s[i0 * 65 + d];
            s1 += qd * k_s[i1 * 65 + d];
            s2 += qd * k_s[i2 * 65 + d];
            s3 += qd * k_s[i3c * 65 + d];
        }
        float sc[4] = {s0, s1, s2, s3};
        float m = -3.0e38f;
#pragma unroll
        for (int rep = 0; rep < 4; ++rep) {
            int i = rep * 64 + l;
            sc[rep] = (i < ILEN) ? sc[rep] * 0.125f : -3.0e38f;
            m = fmaxf(m, sc[rep]);
        }
        for (int mask = 32; mask >= 1; mask >>= 1) m = fmaxf(m, __shfl_xor(m, mask));
        float sum = 0.f;
#pragma unroll
        for (int rep = 0; rep < 4; ++rep) {
            float e = __expf(sc[rep] - m);
            sc[rep] = e;
            sum += e;
        }
        for (int mask = 32; mask >= 1; mask >>= 1) sum += __shfl_xor(sum, mask);
        float inv = 1.f / sum;
        const float* grow = gate + (size_t)(b * 64 + t) * ILEN;
#pragma unroll
        for (int rep = 0; rep < 4; ++rep) {
            int i = rep * 64 + l;
            if (i < ILEN) p_s[w][i][tt] = sc[rep] * inv * grow[i];
        }
    }
    // same wave writes & reads p_s -> no barrier needed

    float ctx[4] = {0.f, 0.f, 0.f, 0.f};
    const float* vbase = v + (size_t)(b * ILEN) * HD + h * DHEAD + l;
#pragma unroll 4
    for (int i = 0; i < ILEN; ++i) {
        float vv = vbase[(size_t)i * HD];
        float4 p4 = *(const float4*)&p_s[w][i][0];
        ctx[0] += p4.x * vv;
        ctx[1] += p4.y * vv;
        ctx[2] += p4.z * vv;
        ctx[3] += p4.w * vv;
    }
#pragma unroll
    for (int tt = 0; tt < 4; ++tt)
        out[(size_t)(b * 64 + tbase + tt) * HD + h * DHEAD + l] = ctx[tt];
}

// ---------------------------------------------------------------------------
extern "C" void kernel_launch(void* const* d_in, const int* in_sizes, int n_in,
                              void* d_out, int out_size, void* d_ws, size_t ws_size,
                              hipStream_t stream)
{
    const float* text  = (const float*)d_in[0];
    const float* image = (const float*)d_in[1];
    const float* Wq = (const float*)d_in[2];
    const float* bq = (const float*)d_in[3];
    const float* Wk = (const float*)d_in[4];
    const float* bk = (const float*)d_in[5];
    const float* Wv = (const float*)d_in[6];
    const float* bv = (const float*)d_in[7];
    const float* Wt = (const float*)d_in[8];
    const float* bt = (const float*)d_in[9];
    const float* Wi = (const float*)d_in[10];
    const float* bi = (const float*)d_in[11];
    const float* W1 = (const float*)d_in[12];
    const float* b1 = (const float*)d_in[13];
    const float* W2 = (const float*)d_in[14];
    const float* b2 = (const float*)d_in[15];
    float* out = (float*)d_out;

    char* ws = (char*)d_ws;
    size_t off = 0;
    auto carve = [&](size_t bytes) -> void* {
        void* p = (void*)(ws + off);
        off += (bytes + 255) & ~(size_t)255;
        return p;
    };
    short* W5s  = (short*)carve((size_t)5 * 144 * 8192 * 2);   // 11.8 MB
    short* W1Bs = (short*)carve((size_t)36 * 32768);           // 1.18 MB
    float* te    = (float*)carve((size_t)512 * 768 * 4);
    float* qb    = (float*)carve((size_t)512 * 768 * 4);
    float* ieb   = (float*)carve((size_t)1576 * 768 * 4);
    float* kb    = (float*)carve((size_t)1576 * 768 * 4);
    float* vb    = (float*)carve((size_t)1576 * 768 * 4);
    float* gateb = (float*)carve((size_t)NPAIRS * 4);
    float* plg   = (float*)carve((size_t)3 * NPAIRS * 4);

    hipLaunchKernelGGL(prep_weights, dim3(756), dim3(256), 0, stream,
                       Wq, Wk, Wv, Wt, Wi, W1, W5s, W1Bs);
    hipLaunchKernelGGL(proj_kernel, dim3(8, 24), dim3(256), 0, stream,
                       text, 512, W5s, 0, bt, bq, (const float*)nullptr,
                       te, qb, (float*)nullptr);
    hipLaunchKernelGGL(proj_kernel, dim3(25, 36), dim3(256), 0, stream,
                       image, 1576, W5s, 2, bi, bk, bv,
                       ieb, kb, vb);
    hipLaunchKernelGGL(gate_gemm, dim3(MTILES * 3), dim3(512), 0, stream,
                       te, ieb, W1Bs, b1, W2, plg);
    hipLaunchKernelGGL(gate_fin, dim3((NPAIRS + 255) / 256), dim3(256), 0, stream,
                       plg, b2, gateb);
    hipLaunchKernelGGL(attn_kernel, dim3(BATCH * NHEADS * 4), dim3(256), 0, stream,
                       qb, kb, vb, gateb, out);
}

// Round 15
// 335.366 us; speedup vs baseline: 1.2038x; 1.0020x over previous
//
#include <hip/hip_runtime.h>
#include <stdint.h>

#define HD 768
#define NHEADS 12
#define DHEAD 64
#define BATCH 8
#define TLEN 64
#define ILEN 197
#define NPAIRS 100864   // = 394*256 exactly
#define MTILES 394

typedef __attribute__((ext_vector_type(8))) short short8;
typedef __attribute__((ext_vector_type(4))) float f32x4;

__device__ __forceinline__ short f2bf(float x) {
    union { float f; uint32_t u; } v; v.f = x;
    uint32_t r = v.u + 0x7FFFu + ((v.u >> 16) & 1u);
    return (short)(r >> 16);
}
__device__ __forceinline__ float bf2f(short s) {
    union { uint32_t u; float f; } v; v.u = ((uint32_t)(unsigned short)s) << 16;
    return v.f;
}
__device__ __forceinline__ uint32_t cvtpk(float lo, float hi) {
    uint32_t r;
    asm("v_cvt_pk_bf16_f32 %0, %1, %2" : "=v"(r) : "v"(lo), "v"(hi));
    return r;
}
__device__ __forceinline__ void gll16(const void* g, void* l) {
    __builtin_amdgcn_global_load_lds(
        (const __attribute__((address_space(1))) unsigned int*)g,
        (__attribute__((address_space(3))) unsigned int*)l, 16, 0, 0);
}

// ---------------------------------------------------------------------------
// Prep: W5s proj chunks (unchanged) + W1Bs gate-GEMM B chunks, ks-major
// layout (R13): chunk (pn,kt) = 32 KB, ks-block (16 KB) contiguous:
//   byte = ks*16384 + col*64 + ((g*16) ^ (((col>>1)&3)<<4)), g = k_in_slice/8.
// ---------------------------------------------------------------------------
__global__ __launch_bounds__(256) void prep_weights(
    const float* __restrict__ Wq, const float* __restrict__ Wk,
    const float* __restrict__ Wv, const float* __restrict__ Wt,
    const float* __restrict__ Wi, const float* __restrict__ W1,
    short* __restrict__ W5s, short* __restrict__ W1Bs)
{
    __shared__ float tile[64][65];
    int bx = blockIdx.x;
    int tid = threadIdx.x;
    if (bx >= 720) {
        int idx = bx - 720;            // 0..35
        int pn = idx / 12, kt = idx - pn * 12;
        int c = tid;                   // col 0..255
        int j = pn * 256 + c;
        char* chunk = (char*)W1Bs + (size_t)idx * 32768;
        int f = (c >> 1) & 3;
#pragma unroll
        for (int ks = 0; ks < 2; ++ks) {
            char* dst = chunk + ks * 16384 + c * 64;
#pragma unroll
            for (int g = 0; g < 4; ++g) {
                short8 o;
#pragma unroll
                for (int e = 0; e < 8; ++e)
                    o[e] = f2bf(W1[(size_t)(kt * 64 + ks * 32 + g * 8 + e) * HD + j]);
                *(short8*)(dst + ((g * 16) ^ (f << 4))) = o;
            }
        }
        return;
    }
    int seg = bx / 144, ti = bx - seg * 144;
    const float* src = (seg == 0) ? Wt : (seg == 1) ? Wq : (seg == 2) ? Wi
                     : (seg == 3) ? Wk : Wv;
    int kt = ti / 12, ntile = ti - kt * 12;
#pragma unroll
    for (int pass = 0; pass < 16; ++pass) {
        int idx = pass * 256 + tid;
        int kk = idx >> 6, nn = idx & 63;
        tile[kk][nn] = src[(size_t)(kt * 64 + kk) * HD + ntile * 64 + nn];
    }
    __syncthreads();
    size_t base = ((size_t)(seg * 12 + ntile) * 12 + kt) * 8192;
#pragma unroll
    for (int pass = 0; pass < 16; ++pass) {
        int idx = pass * 256 + tid;
        int col = idx >> 6, kloc = idx & 63;
        float x = tile[kloc][col];
        short h = f2bf(x);
        short lw = f2bf(x - bf2f(h));
        int sidx = (col * 64 + kloc) ^ ((col & 7) << 3);
        W5s[base + sidx] = h;
        W5s[base + 4096 + sidx] = lw;
    }
}

// ---------------------------------------------------------------------------
// Projection GEMM (hi/lo bf16 split, near-fp32) — unchanged from R3.
// ---------------------------------------------------------------------------
__global__ __launch_bounds__(256, 1) void proj_kernel(
    const float* __restrict__ X, int M,
    const short* __restrict__ W5s, int segbase,
    const float* __restrict__ bias0, const float* __restrict__ bias1,
    const float* __restrict__ bias2,
    float* __restrict__ out0, float* __restrict__ out1, float* __restrict__ out2)
{
    __shared__ __align__(16) short Bs[2][8192];
    int tid = threadIdx.x;
    int l = tid & 63, w = tid >> 6;
    int lo = l & 15, grp = l >> 4;
    int y = blockIdx.y;
    int segl = y / 12, ntile = y - segl * 12;
    int seg = segbase + segl;
    const char* wsrc = (const char*)W5s + (size_t)((seg * 12 + ntile) * 12) * 16384;
    {
        const char* s = wsrc + w * 4096 + l * 16;
        char* d = (char*)&Bs[0][0] + w * 4096;
        gll16(s, d); gll16(s + 1024, d + 1024);
        gll16(s + 2048, d + 2048); gll16(s + 3072, d + 3072);
    }
    int arow = blockIdx.x * 64 + w * 16 + lo;
    bool aok = arow < M;
    const float* xrow = X + (size_t)(aok ? arow : 0) * HD;
    short8 ah[24], al[24];
#pragma unroll
    for (int kc = 0; kc < 24; ++kc) {
        int kb = kc * 32 + grp * 8;
        float4 xa = {0.f, 0.f, 0.f, 0.f}, xb = {0.f, 0.f, 0.f, 0.f};
        if (aok) { xa = *(const float4*)(xrow + kb); xb = *(const float4*)(xrow + kb + 4); }
        float xs[8] = {xa.x, xa.y, xa.z, xa.w, xb.x, xb.y, xb.z, xb.w};
#pragma unroll
        for (int e = 0; e < 8; ++e) {
            short hh = f2bf(xs[e]);
            ah[kc][e] = hh;
            al[kc][e] = f2bf(xs[e] - bf2f(hh));
        }
    }
    __syncthreads();

    f32x4 acc[4];
    f32x4 z4 = {0.f, 0.f, 0.f, 0.f};
#pragma unroll
    for (int js = 0; js < 4; ++js) acc[js] = z4;

#pragma unroll
    for (int kk = 0; kk < 12; ++kk) {
        const short* buf = &Bs[kk & 1][0];
        if (kk < 11) {
            const char* s = wsrc + (size_t)(kk + 1) * 16384 + w * 4096 + l * 16;
            char* d = (char*)&Bs[(kk + 1) & 1][0] + w * 4096;
            gll16(s, d); gll16(s + 1024, d + 1024);
            gll16(s + 2048, d + 2048); gll16(s + 3072, d + 3072);
            asm volatile("s_waitcnt vmcnt(4)" ::: "memory");
        } else {
            asm volatile("s_waitcnt vmcnt(0)" ::: "memory");
        }
        __builtin_amdgcn_s_barrier();
        asm volatile("" ::: "memory");
#pragma unroll
        for (int js = 0; js < 4; ++js) {
            int col = js * 16 + lo;
            int base = col * 64;
            int sw = (col & 7) << 3;
#pragma unroll
            for (int kcl = 0; kcl < 2; ++kcl) {
                int idx = (base + kcl * 32 + grp * 8) ^ sw;
                short8 bh = *(const short8*)&buf[idx];
                short8 bl = *(const short8*)&buf[4096 + idx];
                int kc = kk * 2 + kcl;
                acc[js] = __builtin_amdgcn_mfma_f32_16x16x32_bf16(ah[kc], bh, acc[js], 0, 0, 0);
                acc[js] = __builtin_amdgcn_mfma_f32_16x16x32_bf16(ah[kc], bl, acc[js], 0, 0, 0);
                acc[js] = __builtin_amdgcn_mfma_f32_16x16x32_bf16(al[kc], bh, acc[js], 0, 0, 0);
            }
        }
        asm volatile("s_waitcnt lgkmcnt(0)" ::: "memory");
        __builtin_amdgcn_s_barrier();
        asm volatile("" ::: "memory");
    }
    const float* bp = (segl == 0) ? bias0 : (segl == 1) ? bias1 : bias2;
    float* op = (segl == 0) ? out0 : (segl == 1) ? out1 : out2;
#pragma unroll
    for (int js = 0; js < 4; ++js) {
        int cc = ntile * 64 + js * 16 + lo;
        float bvv = bp[cc];
#pragma unroll
        for (int r = 0; r < 4; ++r) {
            int orow = blockIdx.x * 64 + w * 16 + grp * 4 + r;
            if (orow < M) op[(size_t)orow * HD + cc] = acc[js][r] + bvv;
        }
    }
}

// ---------------------------------------------------------------------------
// gate_gemm: 256x256 tile, BK=64, 8 waves (2Mx4N), per-wave 128x64 out.
// R15 = R14 fused-construct, with the serial tail ELIMINATED: the 8 construct
// units are spread 2-per-phase after each phase's MFMAs (overlapping other
// waves' compute), fed by counted vmcnt. Issue order pinned with
// sched_barrier groups: {4x gll16 B(kt+1)}, {xi0,1}, {xi2,3}, {xi4,5},
// {xi6,7}; phase p waits vmcnt(6-2p) before consuming units 2p,2p+1.
// ---------------------------------------------------------------------------
__global__ __launch_bounds__(512, 1) void gate_gemm(
    const float* __restrict__ te, const float* __restrict__ ie,
    const short* __restrict__ W1Bs, const float* __restrict__ b1,
    const float* __restrict__ W2, float* __restrict__ plg)
{
    __shared__ __align__(16) char lds[131072];   // A dbuf [0,64K), B dbuf [64K,128K)
    __shared__ float te_s[3 * HD];               // up to 3 te rows
    __shared__ int ieoff[256];                   // ie elem offset | (slot<<24)
    int tid = threadIdx.x;
    int lane = tid & 63, wid = tid >> 6;
    int lo = lane & 15, grp = lane >> 4;
    int wr = wid >> 2, wc = wid & 3;
    // bijective XCD swizzle (m204)
    int bx0 = blockIdx.x;
    int nwg = gridDim.x;
    int qq = nwg >> 3, rr8 = nwg & 7;
    int xcd = bx0 & 7;
    int logical = (xcd < rr8 ? xcd * (qq + 1) : rr8 * (qq + 1) + (xcd - rr8) * qq)
                + (bx0 >> 3);
    int m_l = logical / 3, pn = logical - m_l * 3;

    const char* Bg = (const char*)W1Bs + (size_t)pn * 12 * 32768;
    int bt0 = (m_l * 256) / 197;

    // ---- prologue: row tables + te LDS table ----
    if (tid < 256) {
        int p = m_l * 256 + tid;
        int bt = p / 197;
        int i = p - bt * 197;
        int b = bt >> 6;
        ieoff[tid] = (b * 197 + i) * HD | ((bt - bt0) << 24);
    }
    for (int idx = tid; idx < 3 * HD; idx += 512) {
        int r = idx / HD;
        int bt = bt0 + r; if (bt > 511) bt = 511;
        te_s[idx] = te[(size_t)bt * HD + (idx - r * HD)];
    }
    __syncthreads();

    // construct one unit u of A(t) into buffer par, from a preloaded x
    auto constructUnit = [&](int t, int par, int u, float4 x) {
        int w = u * 512 + tid;
        int row = w >> 4, f4 = w & 15;
        int pk = ieoff[row];
        const float* tp = &te_s[(pk >> 24) * HD + t * 64 + f4 * 4];
        float4 tv = *(const float4*)tp;
        uint32_t o0 = cvtpk(x.x * tv.x, x.y * tv.y);
        uint32_t o1 = cvtpk(x.z * tv.z, x.w * tv.w);
        int ks = f4 >> 3, r7 = f4 & 7, g = r7 >> 1, half = r7 & 1;
        char* dst = lds + par * 32768 + ks * 16384 + row * 64
                  + ((g * 16) ^ (((row >> 1) & 3) << 4)) + half * 8;
        uint2 o = {o0, o1};
        *(uint2*)dst = o;
    };
    // prologue full construct of A(0) (serial, once per block)
    {
#pragma unroll
        for (int u = 0; u < 8; ++u) {
            int w = u * 512 + tid;
            int row = w >> 4, f4 = w & 15;
            int pk = ieoff[row];
            float4 x = *(const float4*)(ie + (pk & 0xFFFFFF) + f4 * 4);
            constructUnit(0, 0, u, x);
        }
        const char* s = Bg + tid * 16;
        char* d = lds + 65536 + tid * 16;
        gll16(s, d); gll16(s + 8192, d + 8192);
        gll16(s + 16384, d + 16384); gll16(s + 24576, d + 24576);
    }
    asm volatile("s_waitcnt vmcnt(0) lgkmcnt(0)" ::: "memory");
    __builtin_amdgcn_s_barrier();
    asm volatile("" ::: "memory");

    f32x4 acc[8][4];
    f32x4 z4 = {0.f, 0.f, 0.f, 0.f};
#pragma unroll
    for (int rt = 0; rt < 8; ++rt)
#pragma unroll
        for (int ct = 0; ct < 4; ++ct) acc[rt][ct] = z4;

    for (int kt = 0; kt < 12; ++kt) {
        int par = kt & 1, npar = par ^ 1;
        int aoff = par * 32768;
        int boff = 65536 + par * 32768;
        bool more = kt < 11;

        // ---- tile-top: pinned-order VMEM issue ----
        float4 xi[8];
        if (more) {
            // group 0: B(kt+1) staging (4 gll16)
            const char* s = Bg + (size_t)(kt + 1) * 32768 + tid * 16;
            char* d = lds + 65536 + npar * 32768 + tid * 16;
            gll16(s, d); gll16(s + 8192, d + 8192);
            gll16(s + 16384, d + 16384); gll16(s + 24576, d + 24576);
            __builtin_amdgcn_sched_barrier(0);
            // groups 1..4: xi pairs
#pragma unroll
            for (int pair = 0; pair < 4; ++pair) {
#pragma unroll
                for (int q = 0; q < 2; ++q) {
                    int u = pair * 2 + q;
                    int w = u * 512 + tid;
                    int row = w >> 4, f4 = w & 15;
                    int pk = ieoff[row];
                    xi[u] = *(const float4*)(ie + (pk & 0xFFFFFF) + (kt + 1) * 64 + f4 * 4);
                }
                __builtin_amdgcn_sched_barrier(0);
            }
        }

        // ---- 4 MFMA phases on tile kt; 2 construct units per phase ----
        short8 bfr[4], af[4];
#pragma unroll
        for (int ph = 0; ph < 4; ++ph) {
            int ksp = ph >> 1;          // 0,0,1,1
            int rh  = ph & 1;           // 0,1,0,1
            if (rh == 0) {
#pragma unroll
                for (int ct = 0; ct < 4; ++ct) {
                    int c = wc * 64 + ct * 16 + lo;
                    bfr[ct] = *(const short8*)(lds + boff + ksp * 16384 + c * 64
                                + ((grp * 16) ^ (((c >> 1) & 3) << 4)));
                }
            }
#pragma unroll
            for (int j = 0; j < 4; ++j) {
                int r = wr * 128 + (rh * 4 + j) * 16 + lo;
                af[j] = *(const short8*)(lds + aoff + ksp * 16384 + r * 64
                            + ((grp * 16) ^ (((r >> 1) & 3) << 4)));
            }
            __builtin_amdgcn_s_barrier();
            asm volatile("s_waitcnt lgkmcnt(0)" ::: "memory");
            __builtin_amdgcn_sched_barrier(0);
            __builtin_amdgcn_s_setprio(1);
#pragma unroll
            for (int j = 0; j < 4; ++j)
#pragma unroll
                for (int ct = 0; ct < 4; ++ct)
                    acc[rh * 4 + j][ct] = __builtin_amdgcn_mfma_f32_16x16x32_bf16(
                        af[j], bfr[ct], acc[rh * 4 + j][ct], 0, 0, 0);
            __builtin_amdgcn_s_setprio(0);
            // ---- construct 2 units of A(kt+1), counted vmcnt ----
            if (more) {
                if (ph == 0)      asm volatile("s_waitcnt vmcnt(6)" ::: "memory");
                else if (ph == 1) asm volatile("s_waitcnt vmcnt(4)" ::: "memory");
                else if (ph == 2) asm volatile("s_waitcnt vmcnt(2)" ::: "memory");
                else              asm volatile("s_waitcnt vmcnt(0)" ::: "memory");
                constructUnit(kt + 1, npar, ph * 2,     xi[ph * 2]);
                constructUnit(kt + 1, npar, ph * 2 + 1, xi[ph * 2 + 1]);
            } else if (ph == 3) {
                asm volatile("s_waitcnt vmcnt(0)" ::: "memory");
            }
            if (ph == 3)
                asm volatile("s_waitcnt lgkmcnt(0)" ::: "memory");  // A-writes visible
            __builtin_amdgcn_s_barrier();
            asm volatile("" ::: "memory");
        }
    }

    // epilogue: h = relu(acc + b1); per-wave partial logit over its 64 cols
    float b1v[4], w2v[4];
#pragma unroll
    for (int ct = 0; ct < 4; ++ct) {
        int j = pn * 256 + wc * 64 + ct * 16 + lo;
        b1v[ct] = b1[j]; w2v[ct] = W2[j];
    }
    float pl[8][4];
#pragma unroll
    for (int rt = 0; rt < 8; ++rt)
#pragma unroll
        for (int r = 0; r < 4; ++r) {
            float s = 0.f;
#pragma unroll
            for (int ct = 0; ct < 4; ++ct)
                s += fmaxf(acc[rt][ct][r] + b1v[ct], 0.f) * w2v[ct];
            pl[rt][r] = s;
        }
#pragma unroll
    for (int msk = 1; msk <= 8; msk <<= 1)
#pragma unroll
        for (int rt = 0; rt < 8; ++rt)
#pragma unroll
            for (int r = 0; r < 4; ++r)
                pl[rt][r] += __shfl_xor(pl[rt][r], msk);

    // reduce the 4 wc-wave partials through (now dead) LDS
    __syncthreads();
    float* red = (float*)lds;                       // [8 wid][128 row]
    if (lo == 0) {
#pragma unroll
        for (int rt = 0; rt < 8; ++rt)
#pragma unroll
            for (int r = 0; r < 4; ++r)
                red[wid * 128 + rt * 16 + grp * 4 + r] = pl[rt][r];
    }
    __syncthreads();
    if (tid < 256) {
        int wr_ = tid >> 7, rl = tid & 127;
        float s = red[(wr_ * 4 + 0) * 128 + rl] + red[(wr_ * 4 + 1) * 128 + rl]
                + red[(wr_ * 4 + 2) * 128 + rl] + red[(wr_ * 4 + 3) * 128 + rl];
        plg[(size_t)pn * NPAIRS + (size_t)m_l * 256 + tid] = s;
    }
}

// ---------------------------------------------------------------------------
__global__ __launch_bounds__(256) void gate_fin(
    const float* __restrict__ plg, const float* __restrict__ b2,
    float* __restrict__ gateb)
{
    int idx = blockIdx.x * 256 + threadIdx.x;
    if (idx < NPAIRS) {
        float s = plg[idx] + plg[NPAIRS + idx] + plg[2 * NPAIRS + idx] + b2[0];
        gateb[idx] = 1.f / (1.f + __expf(-s));
    }
}

// ---------------------------------------------------------------------------
// Cross-attention, fp32 VALU. Grid = (b,h,t-quarter) = 384 blocks.
// R9 structure: softmax rows into p_s[w][i][4], single PV pass (1x v reads).
// ---------------------------------------------------------------------------
__global__ __launch_bounds__(256) void attn_kernel(
    const float* __restrict__ q, const float* __restrict__ k,
    const float* __restrict__ v, const float* __restrict__ gate,
    float* __restrict__ out)
{
    __shared__ float k_s[ILEN * 65];
    __shared__ float p_s[4][ILEN][4];   // [wave][i][tt]
    int bx = blockIdx.x;
    int tq = bx & 3;
    int h = (bx >> 2) % NHEADS;
    int b = bx / (4 * NHEADS);
    int tid = threadIdx.x;
    for (int idx = tid; idx < ILEN * DHEAD; idx += 256) {
        int i = idx >> 6, d = idx & 63;
        k_s[i * 65 + d] = k[(size_t)(b * ILEN + i) * HD + h * DHEAD + d];
    }
    __syncthreads();

    int l = tid & 63, w = tid >> 6;
    int tbase = tq * 16 + w * 4;

    for (int tt = 0; tt < 4; ++tt) {
        int t = tbase + tt;
        float qv = q[(size_t)(b * 64 + t) * HD + h * DHEAD + l];
        float s0 = 0.f, s1 = 0.f, s2 = 0.f, s3 = 0.f;
        int i0 = l, i1 = 64 + l, i2 = 128 + l;
        int i3c = (192 + l < ILEN) ? 192 + l : 0;
        for (int d = 0; d < 64; ++d) {
            float qd = __shfl(qv, d);
            s0 += qd * k_s[i0 * 65 + d];
            s1 += qd * k_s[i1 * 65 + d];
            s2 += qd * k_s[i2 * 65 + d];
            s3 += qd * k_s[i3c * 65 + d];
        }
        float sc[4] = {s0, s1, s2, s3};
        float m = -3.0e38f;
#pragma unroll
        for (int rep = 0; rep < 4; ++rep) {
            int i = rep * 64 + l;
            sc[rep] = (i < ILEN) ? sc[rep] * 0.125f : -3.0e38f;
            m = fmaxf(m, sc[rep]);
        }
        for (int mask = 32; mask >= 1; mask >>= 1) m = fmaxf(m, __shfl_xor(m, mask));
        float sum = 0.f;
#pragma unroll
        for (int rep = 0; rep < 4; ++rep) {
            float e = __expf(sc[rep] - m);
            sc[rep] = e;
            sum += e;
        }
        for (int mask = 32; mask >= 1; mask >>= 1) sum += __shfl_xor(sum, mask);
        float inv = 1.f / sum;
        const float* grow = gate + (size_t)(b * 64 + t) * ILEN;
#pragma unroll
        for (int rep = 0; rep < 4; ++rep) {
            int i = rep * 64 + l;
            if (i < ILEN) p_s[w][i][tt] = sc[rep] * inv * grow[i];
        }
    }
    // same wave writes & reads p_s -> no barrier needed

    float ctx[4] = {0.f, 0.f, 0.f, 0.f};
    const float* vbase = v + (size_t)(b * ILEN) * HD + h * DHEAD + l;
#pragma unroll 4
    for (int i = 0; i < ILEN; ++i) {
        float vv = vbase[(size_t)i * HD];
        float4 p4 = *(const float4*)&p_s[w][i][0];
        ctx[0] += p4.x * vv;
        ctx[1] += p4.y * vv;
        ctx[2] += p4.z * vv;
        ctx[3] += p4.w * vv;
    }
#pragma unroll
    for (int tt = 0; tt < 4; ++tt)
        out[(size_t)(b * 64 + tbase + tt) * HD + h * DHEAD + l] = ctx[tt];
}

// ---------------------------------------------------------------------------
extern "C" void kernel_launch(void* const* d_in, const int* in_sizes, int n_in,
                              void* d_out, int out_size, void* d_ws, size_t ws_size,
                              hipStream_t stream)
{
    const float* text  = (const float*)d_in[0];
    const float* image = (const float*)d_in[1];
    const float* Wq = (const float*)d_in[2];
    const float* bq = (const float*)d_in[3];
    const float* Wk = (const float*)d_in[4];
    const float* bk = (const float*)d_in[5];
    const float* Wv = (const float*)d_in[6];
    const float* bv = (const float*)d_in[7];
    const float* Wt = (const float*)d_in[8];
    const float* bt = (const float*)d_in[9];
    const float* Wi = (const float*)d_in[10];
    const float* bi = (const float*)d_in[11];
    const float* W1 = (const float*)d_in[12];
    const float* b1 = (const float*)d_in[13];
    const float* W2 = (const float*)d_in[14];
    const float* b2 = (const float*)d_in[15];
    float* out = (float*)d_out;

    char* ws = (char*)d_ws;
    size_t off = 0;
    auto carve = [&](size_t bytes) -> void* {
        void* p = (void*)(ws + off);
        off += (bytes + 255) & ~(size_t)255;
        return p;
    };
    short* W5s  = (short*)carve((size_t)5 * 144 * 8192 * 2);   // 11.8 MB
    short* W1Bs = (short*)carve((size_t)36 * 32768);           // 1.18 MB
    float* te    = (float*)carve((size_t)512 * 768 * 4);
    float* qb    = (float*)carve((size_t)512 * 768 * 4);
    float* ieb   = (float*)carve((size_t)1576 * 768 * 4);
    float* kb    = (float*)carve((size_t)1576 * 768 * 4);
    float* vb    = (float*)carve((size_t)1576 * 768 * 4);
    float* gateb = (float*)carve((size_t)NPAIRS * 4);
    float* plg   = (float*)carve((size_t)3 * NPAIRS * 4);

    hipLaunchKernelGGL(prep_weights, dim3(756), dim3(256), 0, stream,
                       Wq, Wk, Wv, Wt, Wi, W1, W5s, W1Bs);
    hipLaunchKernelGGL(proj_kernel, dim3(8, 24), dim3(256), 0, stream,
                       text, 512, W5s, 0, bt, bq, (const float*)nullptr,
                       te, qb, (float*)nullptr);
    hipLaunchKernelGGL(proj_kernel, dim3(25, 36), dim3(256), 0, stream,
                       image, 1576, W5s, 2, bi, bk, bv,
                       ieb, kb, vb);
    hipLaunchKernelGGL(gate_gemm, dim3(MTILES * 3), dim3(512), 0, stream,
                       te, ieb, W1Bs, b1, W2, plg);
    hipLaunchKernelGGL(gate_fin, dim3((NPAIRS + 255) / 256), dim3(256), 0, stream,
                       plg, b2, gateb);
    hipLaunchKernelGGL(attn_kernel, dim3(BATCH * NHEADS * 4), dim3(256), 0, stream,
                       qb, kb, vb, gateb, out);
}